// Round 1
// baseline (3786.992 us; speedup 1.0000x reference)
//
#include <hip/hip_runtime.h>
#include <math.h>

// ---------------------------------------------------------------------------
// DTIModel (EGNN + protein head) forward, f32 baseline.
// N=65536 nodes, E=262144 edges, B=2048 graphs, H=128, L=4.
// Strategy: CSR-based segment sums (no f32 atomics in hot path), fused
// per-edge 3-GEMM chain in one kernel (LDS k-major tiles, 4x4 reg blocking),
// same skeleton for node MLP; pooling uses mean-then-affine linearity.
// ---------------------------------------------------------------------------

static constexpr int NN  = 65536;   // nodes
static constexpr int NE  = 262144;  // edges
static constexpr int NB  = 2048;    // graphs
static constexpr int NDF = 32;      // node feat in
static constexpr int EDF = 8;       // edge feat
static constexpr int HD  = 128;     // hidden
static constexpr int NL  = 4;       // egnn layers
static constexpr int PED = 1280;    // protein embed
static constexpr int PHD = 512;     // protein hidden
static constexpr int CHD = 512;     // combined hidden
static constexpr float EPSV = 1e-8f;

static constexpr int ES = 36;  // LDS row stride (f32): 144B rows, 16B-aligned,
                               // 36%32=4 rotates banks across k rows.

__device__ __forceinline__ float sigmoid_f(float x) {
  return __fdividef(1.0f, 1.0f + __expf(-x));
}
__device__ __forceinline__ float silu_f(float x) { return x * sigmoid_f(x); }

__device__ __forceinline__ void fma44(float (&acc)[4][4], const float4 a, const float4 w) {
  const float av[4] = {a.x, a.y, a.z, a.w};
  const float wv[4] = {w.x, w.y, w.z, w.w};
#pragma unroll
  for (int i = 0; i < 4; ++i)
#pragma unroll
    for (int j = 0; j < 4; ++j) acc[i][j] = fmaf(av[i], wv[j], acc[i][j]);
}

// --------------------------- CSR construction ------------------------------

__global__ void hist_kernel(const int* __restrict__ ei, int* __restrict__ deg) {
  const int e = blockIdx.x * 256 + threadIdx.x;
  if (e < NE) atomicAdd(&deg[ei[e]], 1);
}

__global__ __launch_bounds__(1024) void scan_kernel(const int* __restrict__ deg,
                                                    int* __restrict__ row_ptr) {
  __shared__ int wsums[16];
  __shared__ int carry_s;
  const int t = threadIdx.x;
  const int lane = t & 63, wave = t >> 6;
  if (t == 0) { carry_s = 0; row_ptr[0] = 0; }
  __syncthreads();
  for (int c = 0; c < NN / 1024; ++c) {
    const int i = c * 1024 + t;
    int incl = deg[i];
#pragma unroll
    for (int d = 1; d < 64; d <<= 1) {
      const int u = __shfl_up(incl, d, 64);
      if (lane >= d) incl += u;
    }
    if (lane == 63) wsums[wave] = incl;
    __syncthreads();
    if (t == 0) {
      int a = carry_s;
#pragma unroll
      for (int w = 0; w < 16; ++w) { const int tmp = wsums[w]; wsums[w] = a; a += tmp; }
      carry_s = a;
    }
    __syncthreads();
    row_ptr[i + 1] = wsums[wave] + incl;
    __syncthreads();
  }
}

__global__ void fill_kernel(const int* __restrict__ ei, const int* __restrict__ row_ptr,
                            int* __restrict__ fill_pos, int* __restrict__ edge_ids) {
  const int e = blockIdx.x * 256 + threadIdx.x;
  if (e < NE) {
    const int n = ei[e];
    const int s = atomicAdd(&fill_pos[n], 1);
    edge_ids[row_ptr[n] + s] = e;
  }
}

__global__ void pos_copy_kernel(const float* __restrict__ pos, float* __restrict__ pc) {
  const int n = blockIdx.x * 256 + threadIdx.x;
  if (n < NN) {
    const float4 v = make_float4(pos[(size_t)n * 3 + 0], pos[(size_t)n * 3 + 1],
                                 pos[(size_t)n * 3 + 2], 0.0f);
    *(float4*)(pc + (size_t)n * 4) = v;
  }
}

// ------------------------------- emb_in ------------------------------------

__global__ __launch_bounds__(256) void emb_in_kernel(
    const float* __restrict__ x, const float* __restrict__ W,
    const float* __restrict__ B, float* __restrict__ h) {
  __shared__ float xs[NDF * ES];
  const int t = threadIdx.x;
  const int n0 = blockIdx.x * 32;
  {
    const int r = t >> 3;
    const int kq = (t & 7) * 4;
    const float4 v = *(const float4*)(x + (size_t)(n0 + r) * NDF + kq);
    xs[(kq + 0) * ES + r] = v.x;
    xs[(kq + 1) * ES + r] = v.y;
    xs[(kq + 2) * ES + r] = v.z;
    xs[(kq + 3) * ES + r] = v.w;
  }
  __syncthreads();
  const int eg = t & 7, fg = t >> 3;
  float acc[4][4] = {};
  const float* wp = W + fg * 4;
#pragma unroll
  for (int k = 0; k < NDF; ++k) {
    const float4 a = *(const float4*)&xs[k * ES + eg * 4];
    const float4 w = *(const float4*)(wp + (size_t)k * HD);
    fma44(acc, a, w);
  }
  const float4 bv = *(const float4*)(B + fg * 4);
  const float bb[4] = {bv.x, bv.y, bv.z, bv.w};
#pragma unroll
  for (int i = 0; i < 4; ++i) {
    const float4 o = make_float4(acc[i][0] + bb[0], acc[i][1] + bb[1],
                                 acc[i][2] + bb[2], acc[i][3] + bb[3]);
    *(float4*)(h + (size_t)(n0 + eg * 4 + i) * HD + fg * 4) = o;
  }
}

// ---------------------------- edge model -----------------------------------
// 32 edges/WG, 256 threads. e_in [265][32] k-major in LDS (stride ES).
// phase1: m1 = silu(e_in@W1+b1); phase2: m = silu(m1@W2+b2)*sigmoid(m@aw+ab);
// phase3: trans = d_norm * tanh(silu(m@cw1+cb1)@cw2). m1/m2 alias e_in buffer.

__global__ __launch_bounds__(256) void edge_kernel(
    const float* __restrict__ h, const float* __restrict__ pos_cur,
    const float* __restrict__ edge_attr, const int* __restrict__ edge_index,
    const float* __restrict__ W1, const float* __restrict__ B1,
    const float* __restrict__ W2, const float* __restrict__ B2,
    const float* __restrict__ AW, const float* __restrict__ AB,
    const float* __restrict__ CW1, const float* __restrict__ CB1,
    const float* __restrict__ CW2,
    float* __restrict__ m_out, float* __restrict__ trans_out) {
  __shared__ float smem[265 * ES];  // e_in, then m1, then m2 (aliased)
  __shared__ float gbuf[32 * 33];   // per-(edge,fg) partial dot reductions
  __shared__ float gates[32];
  __shared__ float dnb[32 * 4];

  const int t = threadIdx.x;
  const int e0 = blockIdx.x * 32;

  // stage h[row] (k 0..127) and h[col] (k 128..255), k-major
  {
    const int e = t & 31;
    const int which = (t >> 5) & 1;
    const int q = t >> 6;  // 0..3
    const int idx = edge_index[which * NE + e0 + e];
    const float* src = h + (size_t)idx * HD + q * 32;
#pragma unroll
    for (int u = 0; u < 8; ++u) {
      const float4 v = *(const float4*)(src + u * 4);
      const int kb = which * HD + q * 32 + u * 4;
      smem[(kb + 0) * ES + e] = v.x;
      smem[(kb + 1) * ES + e] = v.y;
      smem[(kb + 2) * ES + e] = v.z;
      smem[(kb + 3) * ES + e] = v.w;
    }
  }
  // geometry (radial, unit d) + edge_attr rows
  if (t < 32) {
    const int e = t;
    const int r = edge_index[e0 + e];
    const int c = edge_index[NE + e0 + e];
    const float4 pr = *(const float4*)(pos_cur + (size_t)r * 4);
    const float4 pc = *(const float4*)(pos_cur + (size_t)c * 4);
    const float dx = pr.x - pc.x, dy = pr.y - pc.y, dz = pr.z - pc.z;
    const float radial = dx * dx + dy * dy + dz * dz;
    const float inv = 1.0f / (sqrtf(radial) + EPSV);
    dnb[e * 4 + 0] = dx * inv;
    dnb[e * 4 + 1] = dy * inv;
    dnb[e * 4 + 2] = dz * inv;
    smem[256 * ES + e] = radial;
    const float* ea = edge_attr + (size_t)(e0 + e) * EDF;
#pragma unroll
    for (int j = 0; j < 8; ++j) smem[(257 + j) * ES + e] = ea[j];
  }
  __syncthreads();

  const int eg = t & 7;   // edges eg*4..+3
  const int fg = t >> 3;  // feats fg*4..+3

  float acc[4][4];
#pragma unroll
  for (int i = 0; i < 4; ++i)
#pragma unroll
    for (int j = 0; j < 4; ++j) acc[i][j] = 0.0f;

  // phase 1: K=265
  {
    const float* wp = W1 + fg * 4;
#pragma unroll 4
    for (int k = 0; k < 265; ++k) {
      const float4 a = *(const float4*)&smem[k * ES + eg * 4];
      const float4 w = *(const float4*)(wp + (size_t)k * HD);
      fma44(acc, a, w);
    }
  }
  float mv[4][4];
  {
    const float4 bv = *(const float4*)(B1 + fg * 4);
    const float bb[4] = {bv.x, bv.y, bv.z, bv.w};
#pragma unroll
    for (int i = 0; i < 4; ++i)
#pragma unroll
      for (int j = 0; j < 4; ++j) mv[i][j] = silu_f(acc[i][j] + bb[j]);
  }
  __syncthreads();  // all phase-1 LDS reads done before overwrite
#pragma unroll
  for (int j = 0; j < 4; ++j) {
    const float4 col = make_float4(mv[0][j], mv[1][j], mv[2][j], mv[3][j]);
    *(float4*)&smem[(fg * 4 + j) * ES + eg * 4] = col;
  }
  __syncthreads();

  // phase 2: K=128, then attention gate
#pragma unroll
  for (int i = 0; i < 4; ++i)
#pragma unroll
    for (int j = 0; j < 4; ++j) acc[i][j] = 0.0f;
  {
    const float* wp = W2 + fg * 4;
#pragma unroll 4
    for (int k = 0; k < HD; ++k) {
      const float4 a = *(const float4*)&smem[k * ES + eg * 4];
      const float4 w = *(const float4*)(wp + (size_t)k * HD);
      fma44(acc, a, w);
    }
  }
  {
    const float4 bv = *(const float4*)(B2 + fg * 4);
    const float bb[4] = {bv.x, bv.y, bv.z, bv.w};
#pragma unroll
    for (int i = 0; i < 4; ++i)
#pragma unroll
      for (int j = 0; j < 4; ++j) mv[i][j] = silu_f(acc[i][j] + bb[j]);
  }
  {
    const float4 awv = *(const float4*)(AW + fg * 4);
#pragma unroll
    for (int i = 0; i < 4; ++i)
      gbuf[(eg * 4 + i) * 33 + fg] =
          mv[i][0] * awv.x + mv[i][1] * awv.y + mv[i][2] * awv.z + mv[i][3] * awv.w;
  }
  __syncthreads();
  if (t < 32) {
    float s = 0.0f;
#pragma unroll 8
    for (int w = 0; w < 32; ++w) s += gbuf[t * 33 + w];
    gates[t] = sigmoid_f(s + AB[0]);
  }
  __syncthreads();
#pragma unroll
  for (int i = 0; i < 4; ++i) {
    const float g = gates[eg * 4 + i];
#pragma unroll
    for (int j = 0; j < 4; ++j) mv[i][j] *= g;
    const float4 o = make_float4(mv[i][0], mv[i][1], mv[i][2], mv[i][3]);
    *(float4*)(m_out + (size_t)(e0 + eg * 4 + i) * HD + fg * 4) = o;
  }
#pragma unroll
  for (int j = 0; j < 4; ++j) {
    const float4 col = make_float4(mv[0][j], mv[1][j], mv[2][j], mv[3][j]);
    *(float4*)&smem[(fg * 4 + j) * ES + eg * 4] = col;
  }
  __syncthreads();

  // phase 3: coord model
#pragma unroll
  for (int i = 0; i < 4; ++i)
#pragma unroll
    for (int j = 0; j < 4; ++j) acc[i][j] = 0.0f;
  {
    const float* wp = CW1 + fg * 4;
#pragma unroll 4
    for (int k = 0; k < HD; ++k) {
      const float4 a = *(const float4*)&smem[k * ES + eg * 4];
      const float4 w = *(const float4*)(wp + (size_t)k * HD);
      fma44(acc, a, w);
    }
  }
  float tv[4][4];
  {
    const float4 bv = *(const float4*)(CB1 + fg * 4);
    const float bb[4] = {bv.x, bv.y, bv.z, bv.w};
#pragma unroll
    for (int i = 0; i < 4; ++i)
#pragma unroll
      for (int j = 0; j < 4; ++j) tv[i][j] = silu_f(acc[i][j] + bb[j]);
  }
  {
    const float4 c2 = *(const float4*)(CW2 + fg * 4);
#pragma unroll
    for (int i = 0; i < 4; ++i)
      gbuf[(eg * 4 + i) * 33 + fg] =
          tv[i][0] * c2.x + tv[i][1] * c2.y + tv[i][2] * c2.z + tv[i][3] * c2.w;
  }
  __syncthreads();
  if (t < 32) {
    float s = 0.0f;
#pragma unroll 8
    for (int w = 0; w < 32; ++w) s += gbuf[t * 33 + w];
    const float sc = tanhf(s);
    const float4 tr = make_float4(dnb[t * 4 + 0] * sc, dnb[t * 4 + 1] * sc,
                                  dnb[t * 4 + 2] * sc, 0.0f);
    *(float4*)(trans_out + (size_t)(e0 + t) * 4) = tr;
  }
}

// ------------------------ gather (segment sums) ----------------------------
// one wave per node: agg[n] = sum m[e], pos[n] += mean trans[e]

__global__ __launch_bounds__(256) void gather_kernel(
    const float* __restrict__ m_buf, const float* __restrict__ trans,
    const int* __restrict__ row_ptr, const int* __restrict__ edge_ids,
    float* __restrict__ agg, float* __restrict__ pos_cur) {
  const int t = threadIdx.x;
  const int wave = t >> 6, lane = t & 63;
  const int n = blockIdx.x * 4 + wave;
  const int s = row_ptr[n], e_end = row_ptr[n + 1];
  float a0 = 0.0f, a1 = 0.0f, ta = 0.0f;
  for (int i = s; i < e_end; ++i) {
    const int e = edge_ids[i];
    const float2 v = *(const float2*)(m_buf + (size_t)e * HD + lane * 2);
    a0 += v.x;
    a1 += v.y;
    if (lane < 4) ta += trans[(size_t)e * 4 + lane];
  }
  *(float2*)(agg + (size_t)n * HD + lane * 2) = make_float2(a0, a1);
  if (lane < 3) {
    const int dg = e_end - s;
    pos_cur[(size_t)n * 4 + lane] += ta / (float)(dg > 0 ? dg : 1);
  }
}

// ----------------------------- node model ----------------------------------
// h = h + silu([h,agg]@W1+b1)@W2+b2, 32 nodes/WG, same GEMM skeleton

__global__ __launch_bounds__(256) void node_kernel(
    float* __restrict__ h, const float* __restrict__ agg,
    const float* __restrict__ W1, const float* __restrict__ B1,
    const float* __restrict__ W2, const float* __restrict__ B2) {
  __shared__ float smem[256 * ES];
  const int t = threadIdx.x;
  const int n0 = blockIdx.x * 32;
  {
    const int r = t & 31;
    const int seg = t >> 5;  // 0..7, 16 k each
    const float* hs = h + (size_t)(n0 + r) * HD + seg * 16;
    const float* as = agg + (size_t)(n0 + r) * HD + seg * 16;
#pragma unroll
    for (int u = 0; u < 4; ++u) {
      const int kb = seg * 16 + u * 4;
      const float4 v = *(const float4*)(hs + u * 4);
      smem[(kb + 0) * ES + r] = v.x;
      smem[(kb + 1) * ES + r] = v.y;
      smem[(kb + 2) * ES + r] = v.z;
      smem[(kb + 3) * ES + r] = v.w;
      const float4 w = *(const float4*)(as + u * 4);
      smem[(HD + kb + 0) * ES + r] = w.x;
      smem[(HD + kb + 1) * ES + r] = w.y;
      smem[(HD + kb + 2) * ES + r] = w.z;
      smem[(HD + kb + 3) * ES + r] = w.w;
    }
  }
  __syncthreads();
  const int eg = t & 7, fg = t >> 3;
  float acc[4][4] = {};
  {
    const float* wp = W1 + fg * 4;
#pragma unroll 4
    for (int k = 0; k < 2 * HD; ++k) {
      const float4 a = *(const float4*)&smem[k * ES + eg * 4];
      const float4 w = *(const float4*)(wp + (size_t)k * HD);
      fma44(acc, a, w);
    }
  }
  float mv[4][4];
  {
    const float4 bv = *(const float4*)(B1 + fg * 4);
    const float bb[4] = {bv.x, bv.y, bv.z, bv.w};
#pragma unroll
    for (int i = 0; i < 4; ++i)
#pragma unroll
      for (int j = 0; j < 4; ++j) mv[i][j] = silu_f(acc[i][j] + bb[j]);
  }
  __syncthreads();
#pragma unroll
  for (int j = 0; j < 4; ++j) {
    const float4 col = make_float4(mv[0][j], mv[1][j], mv[2][j], mv[3][j]);
    *(float4*)&smem[(fg * 4 + j) * ES + eg * 4] = col;
  }
  __syncthreads();
#pragma unroll
  for (int i = 0; i < 4; ++i)
#pragma unroll
    for (int j = 0; j < 4; ++j) acc[i][j] = 0.0f;
  {
    const float* wp = W2 + fg * 4;
#pragma unroll 4
    for (int k = 0; k < HD; ++k) {
      const float4 a = *(const float4*)&smem[k * ES + eg * 4];
      const float4 w = *(const float4*)(wp + (size_t)k * HD);
      fma44(acc, a, w);
    }
  }
  {
    const float4 bv = *(const float4*)(B2 + fg * 4);
    const float bb[4] = {bv.x, bv.y, bv.z, bv.w};
#pragma unroll
    for (int i = 0; i < 4; ++i) {
      float* hp = h + (size_t)(n0 + eg * 4 + i) * HD + fg * 4;
      const float4 old = *(const float4*)hp;
      const float4 o = make_float4(old.x + acc[i][0] + bb[0], old.y + acc[i][1] + bb[1],
                                   old.z + acc[i][2] + bb[2], old.w + acc[i][3] + bb[3]);
      *(float4*)hp = o;
    }
  }
}

// ------------------------------ heads --------------------------------------
// mean-pool then emb_out (linearity: mean(h@W+b) = mean(h)@W + b)

__global__ __launch_bounds__(128) void pool_kernel(
    const float* __restrict__ h, const float* __restrict__ W,
    const float* __restrict__ B, float* __restrict__ drug) {
  __shared__ float mh[HD];
  const int g = blockIdx.x, t = threadIdx.x;
  float s = 0.0f;
#pragma unroll 4
  for (int n = 0; n < 32; ++n) s += h[((size_t)g * 32 + n) * HD + t];
  mh[t] = s * (1.0f / 32.0f);
  __syncthreads();
  float acc = B[t];
#pragma unroll 4
  for (int k = 0; k < HD; ++k) acc = fmaf(mh[k], W[(size_t)k * HD + t], acc);
  drug[(size_t)g * HD + t] = acc;
}

__global__ __launch_bounds__(256) void prot_kernel(
    const float* __restrict__ pe, const float* __restrict__ W,
    const float* __restrict__ B, float* __restrict__ out) {
  __shared__ float pin[64 * ES];
  const int t = threadIdx.x;
  const int rb = blockIdx.x * 32;
  const int cb = blockIdx.y * 128;
  const int eg = t & 7, fg = t >> 3;
  float acc[4][4] = {};
  for (int kk = 0; kk < PED; kk += 64) {
    __syncthreads();
    {
      const int r = t >> 3;
      const int kq = (t & 7) * 8;
      const float* src = pe + (size_t)(rb + r) * PED + kk + kq;
      const float4 v0 = *(const float4*)src;
      const float4 v1 = *(const float4*)(src + 4);
      pin[(kq + 0) * ES + r] = v0.x; pin[(kq + 1) * ES + r] = v0.y;
      pin[(kq + 2) * ES + r] = v0.z; pin[(kq + 3) * ES + r] = v0.w;
      pin[(kq + 4) * ES + r] = v1.x; pin[(kq + 5) * ES + r] = v1.y;
      pin[(kq + 6) * ES + r] = v1.z; pin[(kq + 7) * ES + r] = v1.w;
    }
    __syncthreads();
    const float* wp = W + (size_t)kk * PHD + cb + fg * 4;
#pragma unroll 4
    for (int k = 0; k < 64; ++k) {
      const float4 a = *(const float4*)&pin[k * ES + eg * 4];
      const float4 w = *(const float4*)(wp + (size_t)k * PHD);
      fma44(acc, a, w);
    }
  }
  const float4 bv = *(const float4*)(B + cb + fg * 4);
  const float bb[4] = {bv.x, bv.y, bv.z, bv.w};
#pragma unroll
  for (int i = 0; i < 4; ++i) {
    float4 o;
    o.x = fmaxf(acc[i][0] + bb[0], 0.0f);
    o.y = fmaxf(acc[i][1] + bb[1], 0.0f);
    o.z = fmaxf(acc[i][2] + bb[2], 0.0f);
    o.w = fmaxf(acc[i][3] + bb[3], 0.0f);
    *(float4*)(out + (size_t)(rb + eg * 4 + i) * PHD + cb + fg * 4) = o;
  }
}

__global__ __launch_bounds__(256) void comb1_kernel(
    const float* __restrict__ drug, const float* __restrict__ ph,
    const float* __restrict__ W, const float* __restrict__ B,
    float* __restrict__ out) {
  __shared__ float pin[64 * ES];
  const int t = threadIdx.x;
  const int rb = blockIdx.x * 32;
  const int cb = blockIdx.y * 128;
  const int eg = t & 7, fg = t >> 3;
  float acc[4][4] = {};
  for (int kk = 0; kk < HD + PHD; kk += 64) {
    __syncthreads();
    {
      const int r = t >> 3;
      const int kq = (t & 7) * 8;
      const float* src = (kk < HD) ? (drug + (size_t)(rb + r) * HD + kk + kq)
                                   : (ph + (size_t)(rb + r) * PHD + (kk - HD) + kq);
      const float4 v0 = *(const float4*)src;
      const float4 v1 = *(const float4*)(src + 4);
      pin[(kq + 0) * ES + r] = v0.x; pin[(kq + 1) * ES + r] = v0.y;
      pin[(kq + 2) * ES + r] = v0.z; pin[(kq + 3) * ES + r] = v0.w;
      pin[(kq + 4) * ES + r] = v1.x; pin[(kq + 5) * ES + r] = v1.y;
      pin[(kq + 6) * ES + r] = v1.z; pin[(kq + 7) * ES + r] = v1.w;
    }
    __syncthreads();
    const float* wp = W + (size_t)kk * CHD + cb + fg * 4;
#pragma unroll 4
    for (int k = 0; k < 64; ++k) {
      const float4 a = *(const float4*)&pin[k * ES + eg * 4];
      const float4 w = *(const float4*)(wp + (size_t)k * CHD);
      fma44(acc, a, w);
    }
  }
  const float4 bv = *(const float4*)(B + cb + fg * 4);
  const float bb[4] = {bv.x, bv.y, bv.z, bv.w};
#pragma unroll
  for (int i = 0; i < 4; ++i) {
    float4 o;
    o.x = fmaxf(acc[i][0] + bb[0], 0.0f);
    o.y = fmaxf(acc[i][1] + bb[1], 0.0f);
    o.z = fmaxf(acc[i][2] + bb[2], 0.0f);
    o.w = fmaxf(acc[i][3] + bb[3], 0.0f);
    *(float4*)(out + (size_t)(rb + eg * 4 + i) * CHD + cb + fg * 4) = o;
  }
}

__global__ __launch_bounds__(256) void logits_kernel(
    const float* __restrict__ c, const float* __restrict__ w2,
    const float* __restrict__ b2, float* __restrict__ out) {
  const int t = threadIdx.x;
  const int wave = t >> 6, lane = t & 63;
  const int r = blockIdx.x * 4 + wave;
  const float* cp = c + (size_t)r * CHD + lane * 8;
  const float* wp = w2 + lane * 8;
  const float4 a0 = *(const float4*)cp;
  const float4 a1 = *(const float4*)(cp + 4);
  const float4 q0 = *(const float4*)wp;
  const float4 q1 = *(const float4*)(wp + 4);
  float s = a0.x * q0.x + a0.y * q0.y + a0.z * q0.z + a0.w * q0.w +
            a1.x * q1.x + a1.y * q1.y + a1.z * q1.z + a1.w * q1.w;
#pragma unroll
  for (int off = 32; off > 0; off >>= 1) s += __shfl_down(s, off, 64);
  if (lane == 0) {
    out[r] = s + b2[0];
    out[NB + r] = 0.0f;  // attention_weights output = zeros
  }
}

// ------------------------------ launch -------------------------------------

extern "C" void kernel_launch(void* const* d_in, const int* in_sizes, int n_in,
                              void* d_out, int out_size, void* d_ws, size_t ws_size,
                              hipStream_t stream) {
  const float* x          = (const float*)d_in[0];
  const float* pos        = (const float*)d_in[1];
  const float* edge_attr  = (const float*)d_in[2];
  const float* pe         = (const float*)d_in[3];
  const int*   edge_index = (const int*)d_in[4];
  // d_in[5] = batch (unused: batch[i] == i/32, pooling exploits contiguity)
  const float* emb_in_w   = (const float*)d_in[6];
  const float* emb_in_b   = (const float*)d_in[7];
  const float* emb_out_w  = (const float*)d_in[8];
  const float* emb_out_b  = (const float*)d_in[9];
  const float* edge_w1    = (const float*)d_in[10];
  const float* edge_b1    = (const float*)d_in[11];
  const float* edge_w2    = (const float*)d_in[12];
  const float* edge_b2    = (const float*)d_in[13];
  const float* att_w      = (const float*)d_in[14];
  const float* att_b      = (const float*)d_in[15];
  const float* coord_w1   = (const float*)d_in[16];
  const float* coord_b1   = (const float*)d_in[17];
  const float* coord_w2   = (const float*)d_in[18];
  const float* node_w1    = (const float*)d_in[19];
  const float* node_b1    = (const float*)d_in[20];
  const float* node_w2    = (const float*)d_in[21];
  const float* node_b2    = (const float*)d_in[22];
  const float* prot_w     = (const float*)d_in[23];
  const float* prot_b     = (const float*)d_in[24];
  const float* comb_w1    = (const float*)d_in[25];
  const float* comb_b1    = (const float*)d_in[26];
  const float* comb_w2    = (const float*)d_in[27];
  const float* comb_b2    = (const float*)d_in[28];
  float* out = (float*)d_out;
  (void)in_sizes; (void)n_in; (void)out_size; (void)ws_size;

  char* ws = (char*)d_ws;
  size_t off = 0;
  auto carve = [&](size_t bytes) -> void* {
    void* p = ws + off;
    off += (bytes + 255) & ~(size_t)255;
    return p;
  };
  float* h       = (float*)carve((size_t)NN * HD * 4);   // 33.5 MB
  float* agg     = (float*)carve((size_t)NN * HD * 4);   // 33.5 MB
  float* m_buf   = (float*)carve((size_t)NE * HD * 4);   // 134 MB
  float* trans   = (float*)carve((size_t)NE * 4 * 4);    // 4 MB
  float* pos_cur = (float*)carve((size_t)NN * 4 * 4);
  float* drug    = (float*)carve((size_t)NB * HD * 4);
  float* prot_h  = (float*)carve((size_t)NB * PHD * 4);
  float* c_buf   = (float*)carve((size_t)NB * CHD * 4);
  int* deg       = (int*)carve((size_t)NN * 4);
  int* row_ptr   = (int*)carve((size_t)(NN + 1) * 4);
  int* fill_pos  = (int*)carve((size_t)NN * 4);
  int* edge_ids  = (int*)carve((size_t)NE * 4);

  hipMemsetAsync(deg, 0, (size_t)NN * 4, stream);
  hipMemsetAsync(fill_pos, 0, (size_t)NN * 4, stream);

  pos_copy_kernel<<<NN / 256, 256, 0, stream>>>(pos, pos_cur);
  hist_kernel<<<NE / 256, 256, 0, stream>>>(edge_index, deg);
  scan_kernel<<<1, 1024, 0, stream>>>(deg, row_ptr);
  fill_kernel<<<NE / 256, 256, 0, stream>>>(edge_index, row_ptr, fill_pos, edge_ids);
  emb_in_kernel<<<NN / 32, 256, 0, stream>>>(x, emb_in_w, emb_in_b, h);

  for (int l = 0; l < NL; ++l) {
    edge_kernel<<<NE / 32, 256, 0, stream>>>(
        h, pos_cur, edge_attr, edge_index,
        edge_w1 + (size_t)l * 265 * HD, edge_b1 + (size_t)l * HD,
        edge_w2 + (size_t)l * HD * HD, edge_b2 + (size_t)l * HD,
        att_w + (size_t)l * HD, att_b + l,
        coord_w1 + (size_t)l * HD * HD, coord_b1 + (size_t)l * HD,
        coord_w2 + (size_t)l * HD,
        m_buf, trans);
    gather_kernel<<<NN / 4, 256, 0, stream>>>(m_buf, trans, row_ptr, edge_ids,
                                              agg, pos_cur);
    node_kernel<<<NN / 32, 256, 0, stream>>>(
        h, agg,
        node_w1 + (size_t)l * 2 * HD * HD, node_b1 + (size_t)l * HD,
        node_w2 + (size_t)l * HD * HD, node_b2 + (size_t)l * HD);
  }

  pool_kernel<<<NB, 128, 0, stream>>>(h, emb_out_w, emb_out_b, drug);
  prot_kernel<<<dim3(NB / 32, PHD / 128), 256, 0, stream>>>(pe, prot_w, prot_b, prot_h);
  comb1_kernel<<<dim3(NB / 32, CHD / 128), 256, 0, stream>>>(drug, prot_h, comb_w1,
                                                             comb_b1, c_buf);
  logits_kernel<<<NB / 4, 256, 0, stream>>>(c_buf, comb_w2, comb_b2, out);
}

// Round 2
// 1646.133 us; speedup vs baseline: 2.3005x; 2.3005x over previous
//
#include <hip/hip_runtime.h>
#include <math.h>

// ---------------------------------------------------------------------------
// DTIModel (EGNN + protein head) forward.
// R2: edge MLP chain (80% of runtime) moved to bf16 MFMA (16x16x32, f32 acc).
// A-frags gathered directly from global h_bf; weights pre-permuted into
// fragment order; m1/m bounce through XOR-swizzled LDS tile; gate/tanh via
// shfl reductions. Node MLP / heads stay f32 this round.
// ---------------------------------------------------------------------------

static constexpr int NN  = 65536;   // nodes
static constexpr int NE  = 262144;  // edges
static constexpr int NB  = 2048;    // graphs
static constexpr int NDF = 32;      // node feat in
static constexpr int HD  = 128;     // hidden
static constexpr int NL  = 4;       // egnn layers
static constexpr int PED = 1280;    // protein embed
static constexpr int PHD = 512;     // protein hidden
static constexpr int CHD = 512;     // combined hidden
static constexpr float EPSV = 1e-8f;

static constexpr int KK1 = 9;  // ceil(265/32): K-steps for edge GEMM1 (K padded to 288)
static constexpr int KK2 = 4;  // 128/32

static constexpr int ES = 36;  // f32 LDS row stride for the f32 kernels

typedef __attribute__((ext_vector_type(8))) short bf8_t;
typedef __attribute__((ext_vector_type(4))) float f4_t;

__device__ __forceinline__ float sigmoid_f(float x) {
  return __fdividef(1.0f, 1.0f + __expf(-x));
}
__device__ __forceinline__ float silu_f(float x) { return x * sigmoid_f(x); }

__device__ __forceinline__ ushort f2bf(float f) {  // RNE
  unsigned u = __float_as_uint(f);
  u += 0x7FFFu + ((u >> 16) & 1u);
  return (ushort)(u >> 16);
}
__device__ __forceinline__ float bf2f(ushort h) {
  return __uint_as_float(((unsigned)h) << 16);
}

__device__ __forceinline__ void fma44(float (&acc)[4][4], const float4 a, const float4 w) {
  const float av[4] = {a.x, a.y, a.z, a.w};
  const float wv[4] = {w.x, w.y, w.z, w.w};
#pragma unroll
  for (int i = 0; i < 4; ++i)
#pragma unroll
    for (int j = 0; j < 4; ++j) acc[i][j] = fmaf(av[i], wv[j], acc[i][j]);
}

// --------------------------- CSR construction ------------------------------

__global__ void hist_kernel(const int* __restrict__ ei, int* __restrict__ deg) {
  const int e = blockIdx.x * 256 + threadIdx.x;
  if (e < NE) atomicAdd(&deg[ei[e]], 1);
}

__global__ __launch_bounds__(1024) void scan_kernel(const int* __restrict__ deg,
                                                    int* __restrict__ row_ptr) {
  __shared__ int wsums[16];
  __shared__ int carry_s;
  const int t = threadIdx.x;
  const int lane = t & 63, wave = t >> 6;
  if (t == 0) { carry_s = 0; row_ptr[0] = 0; }
  __syncthreads();
  for (int c = 0; c < NN / 1024; ++c) {
    const int i = c * 1024 + t;
    int incl = deg[i];
#pragma unroll
    for (int d = 1; d < 64; d <<= 1) {
      const int u = __shfl_up(incl, d, 64);
      if (lane >= d) incl += u;
    }
    if (lane == 63) wsums[wave] = incl;
    __syncthreads();
    if (t == 0) {
      int a = carry_s;
#pragma unroll
      for (int w = 0; w < 16; ++w) { const int tmp = wsums[w]; wsums[w] = a; a += tmp; }
      carry_s = a;
    }
    __syncthreads();
    row_ptr[i + 1] = wsums[wave] + incl;
    __syncthreads();
  }
}

__global__ void fill_kernel(const int* __restrict__ ei, const int* __restrict__ row_ptr,
                            int* __restrict__ fill_pos, int* __restrict__ edge_ids) {
  const int e = blockIdx.x * 256 + threadIdx.x;
  if (e < NE) {
    const int n = ei[e];
    const int s = atomicAdd(&fill_pos[n], 1);
    edge_ids[row_ptr[n] + s] = e;
  }
}

__global__ void pos_copy_kernel(const float* __restrict__ pos, float* __restrict__ pc) {
  const int n = blockIdx.x * 256 + threadIdx.x;
  if (n < NN) {
    const float4 v = make_float4(pos[(size_t)n * 3 + 0], pos[(size_t)n * 3 + 1],
                                 pos[(size_t)n * 3 + 2], 0.0f);
    *(float4*)(pc + (size_t)n * 4) = v;
  }
}

// ------------------------- weight fragment packing -------------------------
// Wp[((kk*8 + ntg)*64 + l)*8 + e] = bf16(W[k][n]), k = kk*32 + (l>>4)*8 + e,
// n = ntg*16 + (l&15), zero-padded past K. Contiguous-k fill on both A and B
// makes the true HW (group,elem)->k permutation cancel in the MFMA dot.

__global__ __launch_bounds__(256) void packw_kernel(
    const float* __restrict__ W, ushort* __restrict__ Wp,
    int K, int KK, size_t sW, size_t sWp) {
  const int layer = blockIdx.y;
  const int i = blockIdx.x * 256 + threadIdx.x;
  if (i >= KK * 8 * 64) return;
  const int l = i & 63;
  const int k0 = (i >> 9) * 32 + ((l >> 4) * 8);
  const int n = (((i >> 6) & 7) * 16) + (l & 15);
  const float* w = W + layer * sW;
  unsigned ww[4];
#pragma unroll
  for (int p = 0; p < 4; ++p) {
    const int ka = k0 + p * 2, kb = ka + 1;
    const unsigned lo = (ka < K) ? f2bf(w[(size_t)ka * HD + n]) : 0;
    const unsigned hi = (kb < K) ? f2bf(w[(size_t)kb * HD + n]) : 0;
    ww[p] = lo | (hi << 16);
  }
  *(uint4*)(Wp + layer * sWp + (size_t)i * 8) = make_uint4(ww[0], ww[1], ww[2], ww[3]);
}

// ------------------------- per-layer edge geometry -------------------------
// radial/unit-d from current pos; extra_bf[e] = [radial, ea0..7, 0...] (32 bf16)

__global__ __launch_bounds__(256) void geom_kernel(
    const float* __restrict__ pos_cur, const float* __restrict__ edge_attr,
    const int* __restrict__ ei, float* __restrict__ dnb, ushort* __restrict__ extra) {
  const int e = blockIdx.x * 256 + threadIdx.x;
  if (e >= NE) return;
  const int r = ei[e], c = ei[NE + e];
  const float4 pr = *(const float4*)(pos_cur + (size_t)r * 4);
  const float4 pc = *(const float4*)(pos_cur + (size_t)c * 4);
  const float dx = pr.x - pc.x, dy = pr.y - pc.y, dz = pr.z - pc.z;
  const float radial = dx * dx + dy * dy + dz * dz;
  const float inv = 1.0f / (sqrtf(radial) + EPSV);
  *(float4*)(dnb + (size_t)e * 4) = make_float4(dx * inv, dy * inv, dz * inv, 0.0f);
  const float4 ea0 = *(const float4*)(edge_attr + (size_t)e * 8);
  const float4 ea1 = *(const float4*)(edge_attr + (size_t)e * 8 + 4);
  const unsigned w0 = (unsigned)f2bf(radial) | ((unsigned)f2bf(ea0.x) << 16);
  const unsigned w1 = (unsigned)f2bf(ea0.y) | ((unsigned)f2bf(ea0.z) << 16);
  const unsigned w2 = (unsigned)f2bf(ea0.w) | ((unsigned)f2bf(ea1.x) << 16);
  const unsigned w3 = (unsigned)f2bf(ea1.y) | ((unsigned)f2bf(ea1.z) << 16);
  const unsigned w4 = (unsigned)f2bf(ea1.w);
  ushort* dst = extra + (size_t)e * 32;
  *(uint4*)(dst)      = make_uint4(w0, w1, w2, w3);
  *(uint4*)(dst + 8)  = make_uint4(w4, 0, 0, 0);
  *(uint4*)(dst + 16) = make_uint4(0, 0, 0, 0);
  *(uint4*)(dst + 24) = make_uint4(0, 0, 0, 0);
}

// ------------------------------- emb_in ------------------------------------

__global__ __launch_bounds__(256) void emb_in_kernel(
    const float* __restrict__ x, const float* __restrict__ W,
    const float* __restrict__ B, float* __restrict__ h, ushort* __restrict__ hbf) {
  __shared__ float xs[NDF * ES];
  const int t = threadIdx.x;
  const int n0 = blockIdx.x * 32;
  {
    const int r = t >> 3;
    const int kq = (t & 7) * 4;
    const float4 v = *(const float4*)(x + (size_t)(n0 + r) * NDF + kq);
    xs[(kq + 0) * ES + r] = v.x;
    xs[(kq + 1) * ES + r] = v.y;
    xs[(kq + 2) * ES + r] = v.z;
    xs[(kq + 3) * ES + r] = v.w;
  }
  __syncthreads();
  const int eg = t & 7, fg = t >> 3;
  float acc[4][4] = {};
  const float* wp = W + fg * 4;
#pragma unroll
  for (int k = 0; k < NDF; ++k) {
    const float4 a = *(const float4*)&xs[k * ES + eg * 4];
    const float4 w = *(const float4*)(wp + (size_t)k * HD);
    fma44(acc, a, w);
  }
  const float4 bv = *(const float4*)(B + fg * 4);
  const float bb[4] = {bv.x, bv.y, bv.z, bv.w};
#pragma unroll
  for (int i = 0; i < 4; ++i) {
    const float4 o = make_float4(acc[i][0] + bb[0], acc[i][1] + bb[1],
                                 acc[i][2] + bb[2], acc[i][3] + bb[3]);
    *(float4*)(h + (size_t)(n0 + eg * 4 + i) * HD + fg * 4) = o;
    ushort4 hb;
    hb.x = f2bf(o.x); hb.y = f2bf(o.y); hb.z = f2bf(o.z); hb.w = f2bf(o.w);
    *(ushort4*)(hbf + (size_t)(n0 + eg * 4 + i) * HD + fg * 4) = hb;
  }
}

// --------------------------- MFMA edge kernel ------------------------------
// 64 edges x 128 feats per WG; 4 waves as 2(M) x 2(N); per wave 32x64 tile
// (MT=2 x NT=4 fragments of 16x16). GEMM1 K=288 (h_row|h_col|extra),
// A gathered from global h_bf. GEMM2/3 A from swizzled LDS tile.

__global__ __launch_bounds__(256) void edge_mfma_kernel(
    const ushort* __restrict__ hbf, const ushort* __restrict__ extra,
    const int* __restrict__ edge_index, const float* __restrict__ dnb,
    const ushort* __restrict__ W1p, const float* __restrict__ B1,
    const ushort* __restrict__ W2p, const float* __restrict__ B2,
    const float* __restrict__ AW, const float* __restrict__ AB,
    const ushort* __restrict__ CW1p, const float* __restrict__ CB1,
    const float* __restrict__ CW2,
    ushort* __restrict__ m_bf, float* __restrict__ trans_out) {
  __shared__ ushort mtile[64 * 128];  // 16 KB, XOR-swizzled rows (256B)
  __shared__ int ridx[64], cidx[64];
  __shared__ float redbuf[2][64];
  __shared__ float gates[64];

  const int t = threadIdx.x;
  const int e0 = blockIdx.x * 64;
  if (t < 64) {
    ridx[t] = edge_index[e0 + t];
    cidx[t] = edge_index[NE + e0 + t];
  }
  __syncthreads();

  const int w = t >> 6, l = t & 63;
  const int wr = w >> 1, wc = w & 1;
  const int g = l >> 4, ln = l & 15;
  const int row0 = wr * 32;

  int er[2], ec[2], rowA[2];
#pragma unroll
  for (int mt = 0; mt < 2; ++mt) {
    rowA[mt] = row0 + mt * 16 + ln;
    er[mt] = ridx[rowA[mt]];
    ec[mt] = cidx[rowA[mt]];
  }

  const f4_t zf = {0.0f, 0.0f, 0.0f, 0.0f};
  f4_t acc[2][4];
#pragma unroll
  for (int mt = 0; mt < 2; ++mt)
#pragma unroll
    for (int nt = 0; nt < 4; ++nt) acc[mt][nt] = zf;

  // ---- GEMM1: e_in[64 x 288] @ W1p -> m1
#pragma unroll
  for (int kk = 0; kk < KK1; ++kk) {
    bf8_t a[2], b[4];
#pragma unroll
    for (int mt = 0; mt < 2; ++mt) {
      if (kk < 8) {
        const int idx = (kk < 4) ? er[mt] : ec[mt];
        a[mt] = *(const bf8_t*)(hbf + (size_t)idx * HD + (kk & 3) * 32 + g * 8);
      } else {
        a[mt] = *(const bf8_t*)(extra + (size_t)(e0 + rowA[mt]) * 32 + g * 8);
      }
    }
#pragma unroll
    for (int nt = 0; nt < 4; ++nt)
      b[nt] = *(const bf8_t*)(W1p + ((size_t)(kk * 8 + wc * 4 + nt) * 64 + l) * 8);
#pragma unroll
    for (int mt = 0; mt < 2; ++mt)
#pragma unroll
      for (int nt = 0; nt < 4; ++nt)
        acc[mt][nt] = __builtin_amdgcn_mfma_f32_16x16x32_bf16(a[mt], b[nt], acc[mt][nt], 0, 0, 0);
  }

  // m1 = silu(acc + b1), write bf16 to swizzled LDS tile
  {
    float bn[4];
#pragma unroll
    for (int nt = 0; nt < 4; ++nt) bn[nt] = B1[wc * 64 + nt * 16 + ln];
#pragma unroll
    for (int mt = 0; mt < 2; ++mt)
#pragma unroll
      for (int nt = 0; nt < 4; ++nt) {
        const int col = wc * 64 + nt * 16 + ln;
#pragma unroll
        for (int r = 0; r < 4; ++r) {
          const int row = row0 + mt * 16 + g * 4 + r;
          const float v = silu_f(acc[mt][nt][r] + bn[nt]);
          mtile[row * HD + (col ^ ((row & 7) << 3))] = f2bf(v);
        }
      }
  }
  __syncthreads();

  // ---- GEMM2: m1 @ W2p -> m2 (+ sigmoid attention gate)
  f4_t acc2[2][4];
#pragma unroll
  for (int mt = 0; mt < 2; ++mt)
#pragma unroll
    for (int nt = 0; nt < 4; ++nt) acc2[mt][nt] = zf;
#pragma unroll
  for (int kk = 0; kk < KK2; ++kk) {
    bf8_t a[2], b[4];
#pragma unroll
    for (int mt = 0; mt < 2; ++mt) {
      const int ra = rowA[mt];
      const int k0 = kk * 32 + g * 8;
      a[mt] = *(const bf8_t*)&mtile[ra * HD + (k0 ^ ((ra & 7) << 3))];
    }
#pragma unroll
    for (int nt = 0; nt < 4; ++nt)
      b[nt] = *(const bf8_t*)(W2p + ((size_t)(kk * 8 + wc * 4 + nt) * 64 + l) * 8);
#pragma unroll
    for (int mt = 0; mt < 2; ++mt)
#pragma unroll
      for (int nt = 0; nt < 4; ++nt)
        acc2[mt][nt] = __builtin_amdgcn_mfma_f32_16x16x32_bf16(a[mt], b[nt], acc2[mt][nt], 0, 0, 0);
  }

  float m2v[2][4][4];
  {
    float bn[4], awv[4];
#pragma unroll
    for (int nt = 0; nt < 4; ++nt) {
      const int col = wc * 64 + nt * 16 + ln;
      bn[nt] = B2[col];
      awv[nt] = AW[col];
    }
    float p[2][4] = {{0, 0, 0, 0}, {0, 0, 0, 0}};
#pragma unroll
    for (int mt = 0; mt < 2; ++mt)
#pragma unroll
      for (int nt = 0; nt < 4; ++nt)
#pragma unroll
        for (int r = 0; r < 4; ++r) {
          const float v = silu_f(acc2[mt][nt][r] + bn[nt]);
          m2v[mt][nt][r] = v;
          p[mt][r] = fmaf(v, awv[nt], p[mt][r]);
        }
    // reduce over the 16 col-lanes
#pragma unroll
    for (int mt = 0; mt < 2; ++mt)
#pragma unroll
      for (int r = 0; r < 4; ++r) {
#pragma unroll
        for (int d = 1; d < 16; d <<= 1) p[mt][r] += __shfl_xor(p[mt][r], d, 64);
      }
    if (ln == 0) {
#pragma unroll
      for (int mt = 0; mt < 2; ++mt)
#pragma unroll
        for (int r = 0; r < 4; ++r)
          redbuf[wc][row0 + mt * 16 + g * 4 + r] = p[mt][r];
    }
  }
  __syncthreads();
  if (t < 64) gates[t] = sigmoid_f(redbuf[0][t] + redbuf[1][t] + AB[0]);
  __syncthreads();

  // gated m -> swizzled LDS tile
  {
    float grow[2][4];
#pragma unroll
    for (int mt = 0; mt < 2; ++mt)
#pragma unroll
      for (int r = 0; r < 4; ++r) grow[mt][r] = gates[row0 + mt * 16 + g * 4 + r];
#pragma unroll
    for (int mt = 0; mt < 2; ++mt)
#pragma unroll
      for (int nt = 0; nt < 4; ++nt) {
        const int col = wc * 64 + nt * 16 + ln;
#pragma unroll
        for (int r = 0; r < 4; ++r) {
          const int row = row0 + mt * 16 + g * 4 + r;
          mtile[row * HD + (col ^ ((row & 7) << 3))] = f2bf(m2v[mt][nt][r] * grow[mt][r]);
        }
      }
  }
  __syncthreads();

  // ---- GEMM3: m @ CW1p -> t2, coord scalar = tanh(t2 . cw2)
  f4_t acc3[2][4];
#pragma unroll
  for (int mt = 0; mt < 2; ++mt)
#pragma unroll
    for (int nt = 0; nt < 4; ++nt) acc3[mt][nt] = zf;
#pragma unroll
  for (int kk = 0; kk < KK2; ++kk) {
    bf8_t a[2], b[4];
#pragma unroll
    for (int mt = 0; mt < 2; ++mt) {
      const int ra = rowA[mt];
      const int k0 = kk * 32 + g * 8;
      a[mt] = *(const bf8_t*)&mtile[ra * HD + (k0 ^ ((ra & 7) << 3))];
    }
#pragma unroll
    for (int nt = 0; nt < 4; ++nt)
      b[nt] = *(const bf8_t*)(CW1p + ((size_t)(kk * 8 + wc * 4 + nt) * 64 + l) * 8);
#pragma unroll
    for (int mt = 0; mt < 2; ++mt)
#pragma unroll
      for (int nt = 0; nt < 4; ++nt)
        acc3[mt][nt] = __builtin_amdgcn_mfma_f32_16x16x32_bf16(a[mt], b[nt], acc3[mt][nt], 0, 0, 0);
  }
  {
    float cb[4], cwv[4];
#pragma unroll
    for (int nt = 0; nt < 4; ++nt) {
      const int col = wc * 64 + nt * 16 + ln;
      cb[nt] = CB1[col];
      cwv[nt] = CW2[col];
    }
    float q[2][4] = {{0, 0, 0, 0}, {0, 0, 0, 0}};
#pragma unroll
    for (int mt = 0; mt < 2; ++mt)
#pragma unroll
      for (int nt = 0; nt < 4; ++nt)
#pragma unroll
        for (int r = 0; r < 4; ++r) {
          const float v = silu_f(acc3[mt][nt][r] + cb[nt]);
          q[mt][r] = fmaf(v, cwv[nt], q[mt][r]);
        }
#pragma unroll
    for (int mt = 0; mt < 2; ++mt)
#pragma unroll
      for (int r = 0; r < 4; ++r) {
#pragma unroll
        for (int d = 1; d < 16; d <<= 1) q[mt][r] += __shfl_xor(q[mt][r], d, 64);
      }
    if (ln == 0) {
#pragma unroll
      for (int mt = 0; mt < 2; ++mt)
#pragma unroll
        for (int r = 0; r < 4; ++r)
          redbuf[wc][row0 + mt * 16 + g * 4 + r] = q[mt][r];
    }
  }
  __syncthreads();
  if (t < 64) {
    const float s = tanhf(redbuf[0][t] + redbuf[1][t]);
    const f4_t dn = *(const f4_t*)(dnb + (size_t)(e0 + t) * 4);
    const f4_t tr = dn * s;
    *(f4_t*)(trans_out + (size_t)(e0 + t) * 4) = tr;
  }

  // bulk copy gated-m LDS tile -> global m_bf (de-swizzle)
#pragma unroll
  for (int it = 0; it < 4; ++it) {
    const int i = it * 256 + t;   // 1024 chunks of 8 ushort (16B)
    const int row = i >> 4;
    const int c8 = (i & 15) * 8;
    const uint4 v = *(const uint4*)&mtile[row * HD + (c8 ^ ((row & 7) << 3))];
    *(uint4*)(m_bf + (size_t)(e0 + row) * HD + c8) = v;
  }
}

// ------------------------ gather (segment sums) ----------------------------
// one wave per node: agg[n] = sum m[e] (bf16 in, f32 acc), pos += mean trans

__global__ __launch_bounds__(256) void gather_kernel(
    const ushort* __restrict__ m_bf, const float* __restrict__ trans,
    const int* __restrict__ row_ptr, const int* __restrict__ edge_ids,
    float* __restrict__ agg, float* __restrict__ pos_cur) {
  const int t = threadIdx.x;
  const int wave = t >> 6, lane = t & 63;
  const int n = blockIdx.x * 4 + wave;
  const int s = row_ptr[n], e_end = row_ptr[n + 1];
  float a0 = 0.0f, a1 = 0.0f, ta = 0.0f;
  for (int i = s; i < e_end; ++i) {
    const int e = edge_ids[i];
    const ushort2 v = *(const ushort2*)(m_bf + (size_t)e * HD + lane * 2);
    a0 += bf2f(v.x);
    a1 += bf2f(v.y);
    if (lane < 4) ta += trans[(size_t)e * 4 + lane];
  }
  *(float2*)(agg + (size_t)n * HD + lane * 2) = make_float2(a0, a1);
  if (lane < 3) {
    const int dg = e_end - s;
    pos_cur[(size_t)n * 4 + lane] += ta / (float)(dg > 0 ? dg : 1);
  }
}

// ----------------------------- node model ----------------------------------
// h = h + silu([h,agg]@W1+b1)@W2+b2 (f32), also emits h_bf for next layer

__global__ __launch_bounds__(256) void node_kernel(
    float* __restrict__ h, const float* __restrict__ agg,
    const float* __restrict__ W1, const float* __restrict__ B1,
    const float* __restrict__ W2, const float* __restrict__ B2,
    ushort* __restrict__ hbf) {
  __shared__ float smem[256 * ES];
  const int t = threadIdx.x;
  const int n0 = blockIdx.x * 32;
  {
    const int r = t & 31;
    const int seg = t >> 5;
    const float* hs = h + (size_t)(n0 + r) * HD + seg * 16;
    const float* as = agg + (size_t)(n0 + r) * HD + seg * 16;
#pragma unroll
    for (int u = 0; u < 4; ++u) {
      const int kb = seg * 16 + u * 4;
      const float4 v = *(const float4*)(hs + u * 4);
      smem[(kb + 0) * ES + r] = v.x;
      smem[(kb + 1) * ES + r] = v.y;
      smem[(kb + 2) * ES + r] = v.z;
      smem[(kb + 3) * ES + r] = v.w;
      const float4 w2 = *(const float4*)(as + u * 4);
      smem[(HD + kb + 0) * ES + r] = w2.x;
      smem[(HD + kb + 1) * ES + r] = w2.y;
      smem[(HD + kb + 2) * ES + r] = w2.z;
      smem[(HD + kb + 3) * ES + r] = w2.w;
    }
  }
  __syncthreads();
  const int eg = t & 7, fg = t >> 3;
  float acc[4][4] = {};
  {
    const float* wp = W1 + fg * 4;
#pragma unroll 4
    for (int k = 0; k < 2 * HD; ++k) {
      const float4 a = *(const float4*)&smem[k * ES + eg * 4];
      const float4 w2 = *(const float4*)(wp + (size_t)k * HD);
      fma44(acc, a, w2);
    }
  }
  float mv[4][4];
  {
    const float4 bv = *(const float4*)(B1 + fg * 4);
    const float bb[4] = {bv.x, bv.y, bv.z, bv.w};
#pragma unroll
    for (int i = 0; i < 4; ++i)
#pragma unroll
      for (int j = 0; j < 4; ++j) mv[i][j] = silu_f(acc[i][j] + bb[j]);
  }
  __syncthreads();
#pragma unroll
  for (int j = 0; j < 4; ++j) {
    const float4 col = make_float4(mv[0][j], mv[1][j], mv[2][j], mv[3][j]);
    *(float4*)&smem[(fg * 4 + j) * ES + eg * 4] = col;
  }
  __syncthreads();
#pragma unroll
  for (int i = 0; i < 4; ++i)
#pragma unroll
    for (int j = 0; j < 4; ++j) acc[i][j] = 0.0f;
  {
    const float* wp = W2 + fg * 4;
#pragma unroll 4
    for (int k = 0; k < HD; ++k) {
      const float4 a = *(const float4*)&smem[k * ES + eg * 4];
      const float4 w2 = *(const float4*)(wp + (size_t)k * HD);
      fma44(acc, a, w2);
    }
  }
  {
    const float4 bv = *(const float4*)(B2 + fg * 4);
    const float bb[4] = {bv.x, bv.y, bv.z, bv.w};
#pragma unroll
    for (int i = 0; i < 4; ++i) {
      float* hp = h + (size_t)(n0 + eg * 4 + i) * HD + fg * 4;
      const float4 old = *(const float4*)hp;
      const float4 o = make_float4(old.x + acc[i][0] + bb[0], old.y + acc[i][1] + bb[1],
                                   old.z + acc[i][2] + bb[2], old.w + acc[i][3] + bb[3]);
      *(float4*)hp = o;
      ushort4 hb;
      hb.x = f2bf(o.x); hb.y = f2bf(o.y); hb.z = f2bf(o.z); hb.w = f2bf(o.w);
      *(ushort4*)(hbf + (size_t)(n0 + eg * 4 + i) * HD + fg * 4) = hb;
    }
  }
}

// ------------------------------ heads --------------------------------------

__global__ __launch_bounds__(128) void pool_kernel(
    const float* __restrict__ h, const float* __restrict__ W,
    const float* __restrict__ B, float* __restrict__ drug) {
  __shared__ float mh[HD];
  const int g = blockIdx.x, t = threadIdx.x;
  float s = 0.0f;
#pragma unroll 4
  for (int n = 0; n < 32; ++n) s += h[((size_t)g * 32 + n) * HD + t];
  mh[t] = s * (1.0f / 32.0f);
  __syncthreads();
  float acc = B[t];
#pragma unroll 4
  for (int k = 0; k < HD; ++k) acc = fmaf(mh[k], W[(size_t)k * HD + t], acc);
  drug[(size_t)g * HD + t] = acc;
}

__global__ __launch_bounds__(256) void prot_kernel(
    const float* __restrict__ pe, const float* __restrict__ W,
    const float* __restrict__ B, float* __restrict__ out) {
  __shared__ float pin[64 * ES];
  const int t = threadIdx.x;
  const int rb = blockIdx.x * 32;
  const int cb = blockIdx.y * 128;
  const int eg = t & 7, fg = t >> 3;
  float acc[4][4] = {};
  for (int kk = 0; kk < PED; kk += 64) {
    __syncthreads();
    {
      const int r = t >> 3;
      const int kq = (t & 7) * 8;
      const float* src = pe + (size_t)(rb + r) * PED + kk + kq;
      const float4 v0 = *(const float4*)src;
      const float4 v1 = *(const float4*)(src + 4);
      pin[(kq + 0) * ES + r] = v0.x; pin[(kq + 1) * ES + r] = v0.y;
      pin[(kq + 2) * ES + r] = v0.z; pin[(kq + 3) * ES + r] = v0.w;
      pin[(kq + 4) * ES + r] = v1.x; pin[(kq + 5) * ES + r] = v1.y;
      pin[(kq + 6) * ES + r] = v1.z; pin[(kq + 7) * ES + r] = v1.w;
    }
    __syncthreads();
    const float* wp = W + (size_t)kk * PHD + cb + fg * 4;
#pragma unroll 4
    for (int k = 0; k < 64; ++k) {
      const float4 a = *(const float4*)&pin[k * ES + eg * 4];
      const float4 w = *(const float4*)(wp + (size_t)k * PHD);
      fma44(acc, a, w);
    }
  }
  const float4 bv = *(const float4*)(B + cb + fg * 4);
  const float bb[4] = {bv.x, bv.y, bv.z, bv.w};
#pragma unroll
  for (int i = 0; i < 4; ++i) {
    float4 o;
    o.x = fmaxf(acc[i][0] + bb[0], 0.0f);
    o.y = fmaxf(acc[i][1] + bb[1], 0.0f);
    o.z = fmaxf(acc[i][2] + bb[2], 0.0f);
    o.w = fmaxf(acc[i][3] + bb[3], 0.0f);
    *(float4*)(out + (size_t)(rb + eg * 4 + i) * PHD + cb + fg * 4) = o;
  }
}

__global__ __launch_bounds__(256) void comb1_kernel(
    const float* __restrict__ drug, const float* __restrict__ ph,
    const float* __restrict__ W, const float* __restrict__ B,
    float* __restrict__ out) {
  __shared__ float pin[64 * ES];
  const int t = threadIdx.x;
  const int rb = blockIdx.x * 32;
  const int cb = blockIdx.y * 128;
  const int eg = t & 7, fg = t >> 3;
  float acc[4][4] = {};
  for (int kk = 0; kk < HD + PHD; kk += 64) {
    __syncthreads();
    {
      const int r = t >> 3;
      const int kq = (t & 7) * 8;
      const float* src = (kk < HD) ? (drug + (size_t)(rb + r) * HD + kk + kq)
                                   : (ph + (size_t)(rb + r) * PHD + (kk - HD) + kq);
      const float4 v0 = *(const float4*)src;
      const float4 v1 = *(const float4*)(src + 4);
      pin[(kq + 0) * ES + r] = v0.x; pin[(kq + 1) * ES + r] = v0.y;
      pin[(kq + 2) * ES + r] = v0.z; pin[(kq + 3) * ES + r] = v0.w;
      pin[(kq + 4) * ES + r] = v1.x; pin[(kq + 5) * ES + r] = v1.y;
      pin[(kq + 6) * ES + r] = v1.z; pin[(kq + 7) * ES + r] = v1.w;
    }
    __syncthreads();
    const float* wp = W + (size_t)kk * CHD + cb + fg * 4;
#pragma unroll 4
    for (int k = 0; k < 64; ++k) {
      const float4 a = *(const float4*)&pin[k * ES + eg * 4];
      const float4 w = *(const float4*)(wp + (size_t)k * CHD);
      fma44(acc, a, w);
    }
  }
  const float4 bv = *(const float4*)(B + cb + fg * 4);
  const float bb[4] = {bv.x, bv.y, bv.z, bv.w};
#pragma unroll
  for (int i = 0; i < 4; ++i) {
    float4 o;
    o.x = fmaxf(acc[i][0] + bb[0], 0.0f);
    o.y = fmaxf(acc[i][1] + bb[1], 0.0f);
    o.z = fmaxf(acc[i][2] + bb[2], 0.0f);
    o.w = fmaxf(acc[i][3] + bb[3], 0.0f);
    *(float4*)(out + (size_t)(rb + eg * 4 + i) * CHD + cb + fg * 4) = o;
  }
}

__global__ __launch_bounds__(256) void logits_kernel(
    const float* __restrict__ c, const float* __restrict__ w2,
    const float* __restrict__ b2, float* __restrict__ out) {
  const int t = threadIdx.x;
  const int wave = t >> 6, lane = t & 63;
  const int r = blockIdx.x * 4 + wave;
  const float* cp = c + (size_t)r * CHD + lane * 8;
  const float* wp = w2 + lane * 8;
  const float4 a0 = *(const float4*)cp;
  const float4 a1 = *(const float4*)(cp + 4);
  const float4 q0 = *(const float4*)wp;
  const float4 q1 = *(const float4*)(wp + 4);
  float s = a0.x * q0.x + a0.y * q0.y + a0.z * q0.z + a0.w * q0.w +
            a1.x * q1.x + a1.y * q1.y + a1.z * q1.z + a1.w * q1.w;
#pragma unroll
  for (int off = 32; off > 0; off >>= 1) s += __shfl_down(s, off, 64);
  if (lane == 0) {
    out[r] = s + b2[0];
    out[NB + r] = 0.0f;
  }
}

// ------------------------------ launch -------------------------------------

extern "C" void kernel_launch(void* const* d_in, const int* in_sizes, int n_in,
                              void* d_out, int out_size, void* d_ws, size_t ws_size,
                              hipStream_t stream) {
  const float* x          = (const float*)d_in[0];
  const float* pos        = (const float*)d_in[1];
  const float* edge_attr  = (const float*)d_in[2];
  const float* pe         = (const float*)d_in[3];
  const int*   edge_index = (const int*)d_in[4];
  const float* emb_in_w   = (const float*)d_in[6];
  const float* emb_in_b   = (const float*)d_in[7];
  const float* emb_out_w  = (const float*)d_in[8];
  const float* emb_out_b  = (const float*)d_in[9];
  const float* edge_w1    = (const float*)d_in[10];
  const float* edge_b1    = (const float*)d_in[11];
  const float* edge_w2    = (const float*)d_in[12];
  const float* edge_b2    = (const float*)d_in[13];
  const float* att_w      = (const float*)d_in[14];
  const float* att_b      = (const float*)d_in[15];
  const float* coord_w1   = (const float*)d_in[16];
  const float* coord_b1   = (const float*)d_in[17];
  const float* coord_w2   = (const float*)d_in[18];
  const float* node_w1    = (const float*)d_in[19];
  const float* node_b1    = (const float*)d_in[20];
  const float* node_w2    = (const float*)d_in[21];
  const float* node_b2    = (const float*)d_in[22];
  const float* prot_w     = (const float*)d_in[23];
  const float* prot_b     = (const float*)d_in[24];
  const float* comb_w1    = (const float*)d_in[25];
  const float* comb_b1    = (const float*)d_in[26];
  const float* comb_w2    = (const float*)d_in[27];
  const float* comb_b2    = (const float*)d_in[28];
  float* out = (float*)d_out;
  (void)in_sizes; (void)n_in; (void)out_size; (void)ws_size;

  char* ws = (char*)d_ws;
  size_t off = 0;
  auto carve = [&](size_t bytes) -> void* {
    void* p = ws + off;
    off += (bytes + 255) & ~(size_t)255;
    return p;
  };
  float*  h       = (float*)carve((size_t)NN * HD * 4);
  ushort* h_bf    = (ushort*)carve((size_t)NN * HD * 2);
  float*  agg     = (float*)carve((size_t)NN * HD * 4);
  ushort* m_bf    = (ushort*)carve((size_t)NE * HD * 2);
  float*  trans   = (float*)carve((size_t)NE * 4 * 4);
  float*  dnb     = (float*)carve((size_t)NE * 4 * 4);
  ushort* extra   = (ushort*)carve((size_t)NE * 32 * 2);
  float*  pos_cur = (float*)carve((size_t)NN * 4 * 4);
  float*  drug    = (float*)carve((size_t)NB * HD * 4);
  float*  prot_h  = (float*)carve((size_t)NB * PHD * 4);
  float*  c_buf   = (float*)carve((size_t)NB * CHD * 4);
  const size_t sW1p = (size_t)KK1 * 8 * 64 * 8;  // ushorts per layer
  const size_t sW2p = (size_t)KK2 * 8 * 64 * 8;
  ushort* W1p     = (ushort*)carve(sW1p * NL * 2);
  ushort* W2p     = (ushort*)carve(sW2p * NL * 2);
  ushort* CW1p    = (ushort*)carve(sW2p * NL * 2);
  int* deg        = (int*)carve((size_t)NN * 4);
  int* row_ptr    = (int*)carve((size_t)(NN + 1) * 4);
  int* fill_pos   = (int*)carve((size_t)NN * 4);
  int* edge_ids   = (int*)carve((size_t)NE * 4);

  hipMemsetAsync(deg, 0, (size_t)NN * 4, stream);
  hipMemsetAsync(fill_pos, 0, (size_t)NN * 4, stream);

  pos_copy_kernel<<<NN / 256, 256, 0, stream>>>(pos, pos_cur);
  hist_kernel<<<NE / 256, 256, 0, stream>>>(edge_index, deg);
  scan_kernel<<<1, 1024, 0, stream>>>(deg, row_ptr);
  fill_kernel<<<NE / 256, 256, 0, stream>>>(edge_index, row_ptr, fill_pos, edge_ids);

  packw_kernel<<<dim3(18, NL), 256, 0, stream>>>(edge_w1, W1p, 265, KK1,
                                                 (size_t)265 * HD, sW1p);
  packw_kernel<<<dim3(8, NL), 256, 0, stream>>>(edge_w2, W2p, HD, KK2,
                                                (size_t)HD * HD, sW2p);
  packw_kernel<<<dim3(8, NL), 256, 0, stream>>>(coord_w1, CW1p, HD, KK2,
                                                (size_t)HD * HD, sW2p);

  emb_in_kernel<<<NN / 32, 256, 0, stream>>>(x, emb_in_w, emb_in_b, h, h_bf);

  for (int l = 0; l < NL; ++l) {
    geom_kernel<<<NE / 256, 256, 0, stream>>>(pos_cur, edge_attr, edge_index,
                                              dnb, extra);
    edge_mfma_kernel<<<NE / 64, 256, 0, stream>>>(
        h_bf, extra, edge_index, dnb,
        W1p + (size_t)l * sW1p, edge_b1 + (size_t)l * HD,
        W2p + (size_t)l * sW2p, edge_b2 + (size_t)l * HD,
        att_w + (size_t)l * HD, att_b + l,
        CW1p + (size_t)l * sW2p, coord_b1 + (size_t)l * HD,
        coord_w2 + (size_t)l * HD,
        m_bf, trans);
    gather_kernel<<<NN / 4, 256, 0, stream>>>(m_bf, trans, row_ptr, edge_ids,
                                              agg, pos_cur);
    node_kernel<<<NN / 32, 256, 0, stream>>>(
        h, agg,
        node_w1 + (size_t)l * 2 * HD * HD, node_b1 + (size_t)l * HD,
        node_w2 + (size_t)l * HD * HD, node_b2 + (size_t)l * HD, h_bf);
  }

  pool_kernel<<<NB, 128, 0, stream>>>(h, emb_out_w, emb_out_b, drug);
  prot_kernel<<<dim3(NB / 32, PHD / 128), 256, 0, stream>>>(pe, prot_w, prot_b, prot_h);
  comb1_kernel<<<dim3(NB / 32, CHD / 128), 256, 0, stream>>>(drug, prot_h, comb_w1,
                                                             comb_b1, c_buf);
  logits_kernel<<<NB / 4, 256, 0, stream>>>(c_buf, comb_w2, comb_b2, out);
}

// Round 3
// 1094.133 us; speedup vs baseline: 3.4612x; 1.5045x over previous
//
#include <hip/hip_runtime.h>
#include <math.h>

// ---------------------------------------------------------------------------
// DTIModel (EGNN + protein head) forward.
// R3: edge MLP (R2), plus node MLP and protein/combined head GEMMs moved to
// bf16 MFMA (16x16x32, f32 acc) with pre-packed fragment-order weights.
// gather emits bf16 agg; heads fused via c_in = [drug | relu(prot)] bf16.
// ---------------------------------------------------------------------------

static constexpr int NN  = 65536;   // nodes
static constexpr int NE  = 262144;  // edges
static constexpr int NB  = 2048;    // graphs
static constexpr int NDF = 32;      // node feat in
static constexpr int HD  = 128;     // hidden
static constexpr int NL  = 4;       // egnn layers
static constexpr int PED = 1280;    // protein embed
static constexpr int PHD = 512;     // protein hidden
static constexpr int CHD = 512;     // combined hidden
static constexpr float EPSV = 1e-8f;

static constexpr int KK1 = 9;  // ceil(265/32) edge GEMM1
static constexpr int KK2 = 4;  // 128/32
static constexpr int KKN1 = 8; // 256/32 node GEMM1
static constexpr int KKP = 40; // 1280/32 prot
static constexpr int KKC = 20; // 640/32 comb1

static constexpr int ES = 36;  // f32 LDS row stride (emb_in)

typedef __attribute__((ext_vector_type(8))) short bf8_t;
typedef __attribute__((ext_vector_type(4))) float f4_t;

__device__ __forceinline__ float sigmoid_f(float x) {
  return __fdividef(1.0f, 1.0f + __expf(-x));
}
__device__ __forceinline__ float silu_f(float x) { return x * sigmoid_f(x); }

__device__ __forceinline__ ushort f2bf(float f) {  // RNE
  unsigned u = __float_as_uint(f);
  u += 0x7FFFu + ((u >> 16) & 1u);
  return (ushort)(u >> 16);
}
__device__ __forceinline__ float bf2f(ushort h) {
  return __uint_as_float(((unsigned)h) << 16);
}

__device__ __forceinline__ void fma44(float (&acc)[4][4], const float4 a, const float4 w) {
  const float av[4] = {a.x, a.y, a.z, a.w};
  const float wv[4] = {w.x, w.y, w.z, w.w};
#pragma unroll
  for (int i = 0; i < 4; ++i)
#pragma unroll
    for (int j = 0; j < 4; ++j) acc[i][j] = fmaf(av[i], wv[j], acc[i][j]);
}

// --------------------------- CSR construction ------------------------------

__global__ void hist_kernel(const int* __restrict__ ei, int* __restrict__ deg) {
  const int e = blockIdx.x * 256 + threadIdx.x;
  if (e < NE) atomicAdd(&deg[ei[e]], 1);
}

__global__ __launch_bounds__(1024) void scan_kernel(const int* __restrict__ deg,
                                                    int* __restrict__ row_ptr) {
  __shared__ int wsums[16];
  __shared__ int carry_s;
  const int t = threadIdx.x;
  const int lane = t & 63, wave = t >> 6;
  if (t == 0) { carry_s = 0; row_ptr[0] = 0; }
  __syncthreads();
  for (int c = 0; c < NN / 1024; ++c) {
    const int i = c * 1024 + t;
    int incl = deg[i];
#pragma unroll
    for (int d = 1; d < 64; d <<= 1) {
      const int u = __shfl_up(incl, d, 64);
      if (lane >= d) incl += u;
    }
    if (lane == 63) wsums[wave] = incl;
    __syncthreads();
    if (t == 0) {
      int a = carry_s;
#pragma unroll
      for (int w = 0; w < 16; ++w) { const int tmp = wsums[w]; wsums[w] = a; a += tmp; }
      carry_s = a;
    }
    __syncthreads();
    row_ptr[i + 1] = wsums[wave] + incl;
    __syncthreads();
  }
}

__global__ void fill_kernel(const int* __restrict__ ei, const int* __restrict__ row_ptr,
                            int* __restrict__ fill_pos, int* __restrict__ edge_ids) {
  const int e = blockIdx.x * 256 + threadIdx.x;
  if (e < NE) {
    const int n = ei[e];
    const int s = atomicAdd(&fill_pos[n], 1);
    edge_ids[row_ptr[n] + s] = e;
  }
}

__global__ void pos_copy_kernel(const float* __restrict__ pos, float* __restrict__ pc) {
  const int n = blockIdx.x * 256 + threadIdx.x;
  if (n < NN) {
    const float4 v = make_float4(pos[(size_t)n * 3 + 0], pos[(size_t)n * 3 + 1],
                                 pos[(size_t)n * 3 + 2], 0.0f);
    *(float4*)(pc + (size_t)n * 4) = v;
  }
}

// ------------------------- weight fragment packing -------------------------
// Wp[((kk*NTG + ntg)*64 + l)*8 + e] = bf16(W[k][n]), k = kk*32+(l>>4)*8+e,
// n = ntg*16+(l&15), zero-padded past K. Contiguous-k fill on A and B makes
// the HW (group,elem)->k permutation cancel in the MFMA dot.

__global__ __launch_bounds__(256) void packw_kernel(
    const float* __restrict__ W, ushort* __restrict__ Wp,
    int K, int N, int KK, size_t sW, size_t sWp) {
  const int layer = blockIdx.y;
  const int NTG = N >> 4;
  const int i = blockIdx.x * 256 + threadIdx.x;
  if (i >= KK * NTG * 64) return;
  const int l = i & 63;
  const int q = i >> 6;
  const int ntg = q % NTG;
  const int kk = q / NTG;
  const int k0 = kk * 32 + ((l >> 4) * 8);
  const int n = ntg * 16 + (l & 15);
  const float* w = W + layer * sW;
  unsigned ww[4];
#pragma unroll
  for (int p = 0; p < 4; ++p) {
    const int ka = k0 + p * 2, kb = ka + 1;
    const unsigned lo = (ka < K) ? f2bf(w[(size_t)ka * N + n]) : 0;
    const unsigned hi = (kb < K) ? f2bf(w[(size_t)kb * N + n]) : 0;
    ww[p] = lo | (hi << 16);
  }
  *(uint4*)(Wp + layer * sWp + (size_t)i * 8) = make_uint4(ww[0], ww[1], ww[2], ww[3]);
}

// f32 -> bf16 bulk convert (n multiple of 2048)
__global__ __launch_bounds__(256) void cvt_bf_kernel(const float* __restrict__ in,
                                                     ushort* __restrict__ out, int n) {
  const int i = blockIdx.x * 256 + threadIdx.x;
  if (i * 8 >= n) return;
  const float4 v0 = *(const float4*)(in + (size_t)i * 8);
  const float4 v1 = *(const float4*)(in + (size_t)i * 8 + 4);
  unsigned w0 = (unsigned)f2bf(v0.x) | ((unsigned)f2bf(v0.y) << 16);
  unsigned w1 = (unsigned)f2bf(v0.z) | ((unsigned)f2bf(v0.w) << 16);
  unsigned w2 = (unsigned)f2bf(v1.x) | ((unsigned)f2bf(v1.y) << 16);
  unsigned w3 = (unsigned)f2bf(v1.z) | ((unsigned)f2bf(v1.w) << 16);
  *(uint4*)(out + (size_t)i * 8) = make_uint4(w0, w1, w2, w3);
}

// ------------------------- per-layer edge geometry -------------------------

__global__ __launch_bounds__(256) void geom_kernel(
    const float* __restrict__ pos_cur, const float* __restrict__ edge_attr,
    const int* __restrict__ ei, float* __restrict__ dnb, ushort* __restrict__ extra) {
  const int e = blockIdx.x * 256 + threadIdx.x;
  if (e >= NE) return;
  const int r = ei[e], c = ei[NE + e];
  const float4 pr = *(const float4*)(pos_cur + (size_t)r * 4);
  const float4 pc = *(const float4*)(pos_cur + (size_t)c * 4);
  const float dx = pr.x - pc.x, dy = pr.y - pc.y, dz = pr.z - pc.z;
  const float radial = dx * dx + dy * dy + dz * dz;
  const float inv = 1.0f / (sqrtf(radial) + EPSV);
  *(float4*)(dnb + (size_t)e * 4) = make_float4(dx * inv, dy * inv, dz * inv, 0.0f);
  const float4 ea0 = *(const float4*)(edge_attr + (size_t)e * 8);
  const float4 ea1 = *(const float4*)(edge_attr + (size_t)e * 8 + 4);
  const unsigned w0 = (unsigned)f2bf(radial) | ((unsigned)f2bf(ea0.x) << 16);
  const unsigned w1 = (unsigned)f2bf(ea0.y) | ((unsigned)f2bf(ea0.z) << 16);
  const unsigned w2 = (unsigned)f2bf(ea0.w) | ((unsigned)f2bf(ea1.x) << 16);
  const unsigned w3 = (unsigned)f2bf(ea1.y) | ((unsigned)f2bf(ea1.z) << 16);
  const unsigned w4 = (unsigned)f2bf(ea1.w);
  ushort* dst = extra + (size_t)e * 32;
  *(uint4*)(dst)      = make_uint4(w0, w1, w2, w3);
  *(uint4*)(dst + 8)  = make_uint4(w4, 0, 0, 0);
  *(uint4*)(dst + 16) = make_uint4(0, 0, 0, 0);
  *(uint4*)(dst + 24) = make_uint4(0, 0, 0, 0);
}

// ------------------------------- emb_in ------------------------------------

__global__ __launch_bounds__(256) void emb_in_kernel(
    const float* __restrict__ x, const float* __restrict__ W,
    const float* __restrict__ B, float* __restrict__ h, ushort* __restrict__ hbf) {
  __shared__ float xs[NDF * ES];
  const int t = threadIdx.x;
  const int n0 = blockIdx.x * 32;
  {
    const int r = t >> 3;
    const int kq = (t & 7) * 4;
    const float4 v = *(const float4*)(x + (size_t)(n0 + r) * NDF + kq);
    xs[(kq + 0) * ES + r] = v.x;
    xs[(kq + 1) * ES + r] = v.y;
    xs[(kq + 2) * ES + r] = v.z;
    xs[(kq + 3) * ES + r] = v.w;
  }
  __syncthreads();
  const int eg = t & 7, fg = t >> 3;
  float acc[4][4] = {};
  const float* wp = W + fg * 4;
#pragma unroll
  for (int k = 0; k < NDF; ++k) {
    const float4 a = *(const float4*)&xs[k * ES + eg * 4];
    const float4 w = *(const float4*)(wp + (size_t)k * HD);
    fma44(acc, a, w);
  }
  const float4 bv = *(const float4*)(B + fg * 4);
  const float bb[4] = {bv.x, bv.y, bv.z, bv.w};
#pragma unroll
  for (int i = 0; i < 4; ++i) {
    const float4 o = make_float4(acc[i][0] + bb[0], acc[i][1] + bb[1],
                                 acc[i][2] + bb[2], acc[i][3] + bb[3]);
    *(float4*)(h + (size_t)(n0 + eg * 4 + i) * HD + fg * 4) = o;
    ushort4 hb;
    hb.x = f2bf(o.x); hb.y = f2bf(o.y); hb.z = f2bf(o.z); hb.w = f2bf(o.w);
    *(ushort4*)(hbf + (size_t)(n0 + eg * 4 + i) * HD + fg * 4) = hb;
  }
}

// --------------------------- MFMA edge kernel ------------------------------

__global__ __launch_bounds__(256) void edge_mfma_kernel(
    const ushort* __restrict__ hbf, const ushort* __restrict__ extra,
    const int* __restrict__ edge_index, const float* __restrict__ dnb,
    const ushort* __restrict__ W1p, const float* __restrict__ B1,
    const ushort* __restrict__ W2p, const float* __restrict__ B2,
    const float* __restrict__ AW, const float* __restrict__ AB,
    const ushort* __restrict__ CW1p, const float* __restrict__ CB1,
    const float* __restrict__ CW2,
    ushort* __restrict__ m_bf, float* __restrict__ trans_out) {
  __shared__ ushort mtile[64 * 128];  // 16 KB, XOR-swizzled rows
  __shared__ int ridx[64], cidx[64];
  __shared__ float redbuf[2][64];
  __shared__ float gates[64];

  const int t = threadIdx.x;
  const int e0 = blockIdx.x * 64;
  if (t < 64) {
    ridx[t] = edge_index[e0 + t];
    cidx[t] = edge_index[NE + e0 + t];
  }
  __syncthreads();

  const int w = t >> 6, l = t & 63;
  const int wr = w >> 1, wc = w & 1;
  const int g = l >> 4, ln = l & 15;
  const int row0 = wr * 32;

  int er[2], ec[2], rowA[2];
#pragma unroll
  for (int mt = 0; mt < 2; ++mt) {
    rowA[mt] = row0 + mt * 16 + ln;
    er[mt] = ridx[rowA[mt]];
    ec[mt] = cidx[rowA[mt]];
  }

  const f4_t zf = {0.0f, 0.0f, 0.0f, 0.0f};
  f4_t acc[2][4];
#pragma unroll
  for (int mt = 0; mt < 2; ++mt)
#pragma unroll
    for (int nt = 0; nt < 4; ++nt) acc[mt][nt] = zf;

  // ---- GEMM1: e_in[64 x 288] @ W1p -> m1
#pragma unroll
  for (int kk = 0; kk < KK1; ++kk) {
    bf8_t a[2], b[4];
#pragma unroll
    for (int mt = 0; mt < 2; ++mt) {
      if (kk < 8) {
        const int idx = (kk < 4) ? er[mt] : ec[mt];
        a[mt] = *(const bf8_t*)(hbf + (size_t)idx * HD + (kk & 3) * 32 + g * 8);
      } else {
        a[mt] = *(const bf8_t*)(extra + (size_t)(e0 + rowA[mt]) * 32 + g * 8);
      }
    }
#pragma unroll
    for (int nt = 0; nt < 4; ++nt)
      b[nt] = *(const bf8_t*)(W1p + ((size_t)(kk * 8 + wc * 4 + nt) * 64 + l) * 8);
#pragma unroll
    for (int mt = 0; mt < 2; ++mt)
#pragma unroll
      for (int nt = 0; nt < 4; ++nt)
        acc[mt][nt] = __builtin_amdgcn_mfma_f32_16x16x32_bf16(a[mt], b[nt], acc[mt][nt], 0, 0, 0);
  }

  {
    float bn[4];
#pragma unroll
    for (int nt = 0; nt < 4; ++nt) bn[nt] = B1[wc * 64 + nt * 16 + ln];
#pragma unroll
    for (int mt = 0; mt < 2; ++mt)
#pragma unroll
      for (int nt = 0; nt < 4; ++nt) {
        const int col = wc * 64 + nt * 16 + ln;
#pragma unroll
        for (int r = 0; r < 4; ++r) {
          const int row = row0 + mt * 16 + g * 4 + r;
          const float v = silu_f(acc[mt][nt][r] + bn[nt]);
          mtile[row * HD + (col ^ ((row & 7) << 3))] = f2bf(v);
        }
      }
  }
  __syncthreads();

  // ---- GEMM2: m1 @ W2p -> m2 (+ sigmoid attention gate)
  f4_t acc2[2][4];
#pragma unroll
  for (int mt = 0; mt < 2; ++mt)
#pragma unroll
    for (int nt = 0; nt < 4; ++nt) acc2[mt][nt] = zf;
#pragma unroll
  for (int kk = 0; kk < KK2; ++kk) {
    bf8_t a[2], b[4];
#pragma unroll
    for (int mt = 0; mt < 2; ++mt) {
      const int ra = rowA[mt];
      const int k0 = kk * 32 + g * 8;
      a[mt] = *(const bf8_t*)&mtile[ra * HD + (k0 ^ ((ra & 7) << 3))];
    }
#pragma unroll
    for (int nt = 0; nt < 4; ++nt)
      b[nt] = *(const bf8_t*)(W2p + ((size_t)(kk * 8 + wc * 4 + nt) * 64 + l) * 8);
#pragma unroll
    for (int mt = 0; mt < 2; ++mt)
#pragma unroll
      for (int nt = 0; nt < 4; ++nt)
        acc2[mt][nt] = __builtin_amdgcn_mfma_f32_16x16x32_bf16(a[mt], b[nt], acc2[mt][nt], 0, 0, 0);
  }

  float m2v[2][4][4];
  {
    float bn[4], awv[4];
#pragma unroll
    for (int nt = 0; nt < 4; ++nt) {
      const int col = wc * 64 + nt * 16 + ln;
      bn[nt] = B2[col];
      awv[nt] = AW[col];
    }
    float p[2][4] = {{0, 0, 0, 0}, {0, 0, 0, 0}};
#pragma unroll
    for (int mt = 0; mt < 2; ++mt)
#pragma unroll
      for (int nt = 0; nt < 4; ++nt)
#pragma unroll
        for (int r = 0; r < 4; ++r) {
          const float v = silu_f(acc2[mt][nt][r] + bn[nt]);
          m2v[mt][nt][r] = v;
          p[mt][r] = fmaf(v, awv[nt], p[mt][r]);
        }
#pragma unroll
    for (int mt = 0; mt < 2; ++mt)
#pragma unroll
      for (int r = 0; r < 4; ++r) {
#pragma unroll
        for (int d = 1; d < 16; d <<= 1) p[mt][r] += __shfl_xor(p[mt][r], d, 64);
      }
    if (ln == 0) {
#pragma unroll
      for (int mt = 0; mt < 2; ++mt)
#pragma unroll
        for (int r = 0; r < 4; ++r)
          redbuf[wc][row0 + mt * 16 + g * 4 + r] = p[mt][r];
    }
  }
  __syncthreads();
  if (t < 64) gates[t] = sigmoid_f(redbuf[0][t] + redbuf[1][t] + AB[0]);
  __syncthreads();

  {
    float grow[2][4];
#pragma unroll
    for (int mt = 0; mt < 2; ++mt)
#pragma unroll
      for (int r = 0; r < 4; ++r) grow[mt][r] = gates[row0 + mt * 16 + g * 4 + r];
#pragma unroll
    for (int mt = 0; mt < 2; ++mt)
#pragma unroll
      for (int nt = 0; nt < 4; ++nt) {
        const int col = wc * 64 + nt * 16 + ln;
#pragma unroll
        for (int r = 0; r < 4; ++r) {
          const int row = row0 + mt * 16 + g * 4 + r;
          mtile[row * HD + (col ^ ((row & 7) << 3))] = f2bf(m2v[mt][nt][r] * grow[mt][r]);
        }
      }
  }
  __syncthreads();

  // ---- GEMM3: m @ CW1p -> t2, coord scalar = tanh(t2 . cw2)
  f4_t acc3[2][4];
#pragma unroll
  for (int mt = 0; mt < 2; ++mt)
#pragma unroll
    for (int nt = 0; nt < 4; ++nt) acc3[mt][nt] = zf;
#pragma unroll
  for (int kk = 0; kk < KK2; ++kk) {
    bf8_t a[2], b[4];
#pragma unroll
    for (int mt = 0; mt < 2; ++mt) {
      const int ra = rowA[mt];
      const int k0 = kk * 32 + g * 8;
      a[mt] = *(const bf8_t*)&mtile[ra * HD + (k0 ^ ((ra & 7) << 3))];
    }
#pragma unroll
    for (int nt = 0; nt < 4; ++nt)
      b[nt] = *(const bf8_t*)(CW1p + ((size_t)(kk * 8 + wc * 4 + nt) * 64 + l) * 8);
#pragma unroll
    for (int mt = 0; mt < 2; ++mt)
#pragma unroll
      for (int nt = 0; nt < 4; ++nt)
        acc3[mt][nt] = __builtin_amdgcn_mfma_f32_16x16x32_bf16(a[mt], b[nt], acc3[mt][nt], 0, 0, 0);
  }
  {
    float cb[4], cwv[4];
#pragma unroll
    for (int nt = 0; nt < 4; ++nt) {
      const int col = wc * 64 + nt * 16 + ln;
      cb[nt] = CB1[col];
      cwv[nt] = CW2[col];
    }
    float q[2][4] = {{0, 0, 0, 0}, {0, 0, 0, 0}};
#pragma unroll
    for (int mt = 0; mt < 2; ++mt)
#pragma unroll
      for (int nt = 0; nt < 4; ++nt)
#pragma unroll
        for (int r = 0; r < 4; ++r) {
          const float v = silu_f(acc3[mt][nt][r] + cb[nt]);
          q[mt][r] = fmaf(v, cwv[nt], q[mt][r]);
        }
#pragma unroll
    for (int mt = 0; mt < 2; ++mt)
#pragma unroll
      for (int r = 0; r < 4; ++r) {
#pragma unroll
        for (int d = 1; d < 16; d <<= 1) q[mt][r] += __shfl_xor(q[mt][r], d, 64);
      }
    if (ln == 0) {
#pragma unroll
      for (int mt = 0; mt < 2; ++mt)
#pragma unroll
        for (int r = 0; r < 4; ++r)
          redbuf[wc][row0 + mt * 16 + g * 4 + r] = q[mt][r];
    }
  }
  __syncthreads();
  if (t < 64) {
    const float s = tanhf(redbuf[0][t] + redbuf[1][t]);
    const f4_t dn = *(const f4_t*)(dnb + (size_t)(e0 + t) * 4);
    const f4_t tr = dn * s;
    *(f4_t*)(trans_out + (size_t)(e0 + t) * 4) = tr;
  }

#pragma unroll
  for (int it = 0; it < 4; ++it) {
    const int i = it * 256 + t;
    const int row = i >> 4;
    const int c8 = (i & 15) * 8;
    const uint4 v = *(const uint4*)&mtile[row * HD + (c8 ^ ((row & 7) << 3))];
    *(uint4*)(m_bf + (size_t)(e0 + row) * HD + c8) = v;
  }
}

// ------------------------ gather (segment sums) ----------------------------
// one wave per node: agg_bf[n] = bf16(sum m[e]), pos += mean trans

__global__ __launch_bounds__(256) void gather_kernel(
    const ushort* __restrict__ m_bf, const float* __restrict__ trans,
    const int* __restrict__ row_ptr, const int* __restrict__ edge_ids,
    ushort* __restrict__ agg_bf, float* __restrict__ pos_cur) {
  const int t = threadIdx.x;
  const int wave = t >> 6, lane = t & 63;
  const int n = blockIdx.x * 4 + wave;
  const int s = row_ptr[n], e_end = row_ptr[n + 1];
  float a0 = 0.0f, a1 = 0.0f, ta = 0.0f;
  for (int i = s; i < e_end; ++i) {
    const int e = edge_ids[i];
    const ushort2 v = *(const ushort2*)(m_bf + (size_t)e * HD + lane * 2);
    a0 += bf2f(v.x);
    a1 += bf2f(v.y);
    if (lane < 4) ta += trans[(size_t)e * 4 + lane];
  }
  ushort2 ab;
  ab.x = f2bf(a0);
  ab.y = f2bf(a1);
  *(ushort2*)(agg_bf + (size_t)n * HD + lane * 2) = ab;
  if (lane < 3) {
    const int dg = e_end - s;
    pos_cur[(size_t)n * 4 + lane] += ta / (float)(dg > 0 ? dg : 1);
  }
}

// --------------------------- MFMA node kernel ------------------------------
// 64 nodes x 128 feats per WG; GEMM1 K=256 ([h|agg] bf16 from global),
// GEMM2 K=128 via swizzled LDS; residual h update in f32; emits h_bf.

__global__ __launch_bounds__(256) void node_mfma_kernel(
    float* __restrict__ h, const ushort* __restrict__ hbf,
    const ushort* __restrict__ agg_bf,
    const ushort* __restrict__ W1p, const float* __restrict__ B1,
    const ushort* __restrict__ W2p, const float* __restrict__ B2,
    ushort* __restrict__ hbf_out) {
  __shared__ ushort mtile[64 * 128];
  const int t = threadIdx.x;
  const int n0 = blockIdx.x * 64;
  const int w = t >> 6, l = t & 63;
  const int wr = w >> 1, wc = w & 1;
  const int g = l >> 4, ln = l & 15;
  const int row0 = wr * 32;
  int rowA[2];
#pragma unroll
  for (int mt = 0; mt < 2; ++mt) rowA[mt] = row0 + mt * 16 + ln;

  const f4_t zf = {0.0f, 0.0f, 0.0f, 0.0f};
  f4_t acc[2][4];
#pragma unroll
  for (int mt = 0; mt < 2; ++mt)
#pragma unroll
    for (int nt = 0; nt < 4; ++nt) acc[mt][nt] = zf;

  // GEMM1: [h|agg] @ W1p, K=256
#pragma unroll
  for (int kk = 0; kk < KKN1; ++kk) {
    bf8_t a[2], b[4];
#pragma unroll
    for (int mt = 0; mt < 2; ++mt) {
      const size_t base = (size_t)(n0 + rowA[mt]) * HD + (kk & 3) * 32 + g * 8;
      a[mt] = (kk < 4) ? *(const bf8_t*)(hbf + base) : *(const bf8_t*)(agg_bf + base);
    }
#pragma unroll
    for (int nt = 0; nt < 4; ++nt)
      b[nt] = *(const bf8_t*)(W1p + ((size_t)(kk * 8 + wc * 4 + nt) * 64 + l) * 8);
#pragma unroll
    for (int mt = 0; mt < 2; ++mt)
#pragma unroll
      for (int nt = 0; nt < 4; ++nt)
        acc[mt][nt] = __builtin_amdgcn_mfma_f32_16x16x32_bf16(a[mt], b[nt], acc[mt][nt], 0, 0, 0);
  }
  {
    float bn[4];
#pragma unroll
    for (int nt = 0; nt < 4; ++nt) bn[nt] = B1[wc * 64 + nt * 16 + ln];
#pragma unroll
    for (int mt = 0; mt < 2; ++mt)
#pragma unroll
      for (int nt = 0; nt < 4; ++nt) {
        const int col = wc * 64 + nt * 16 + ln;
#pragma unroll
        for (int r = 0; r < 4; ++r) {
          const int row = row0 + mt * 16 + g * 4 + r;
          const float v = silu_f(acc[mt][nt][r] + bn[nt]);
          mtile[row * HD + (col ^ ((row & 7) << 3))] = f2bf(v);
        }
      }
  }
  __syncthreads();

  // GEMM2: nh @ W2p, K=128; h += out + b2
  f4_t acc2[2][4];
#pragma unroll
  for (int mt = 0; mt < 2; ++mt)
#pragma unroll
    for (int nt = 0; nt < 4; ++nt) acc2[mt][nt] = zf;
#pragma unroll
  for (int kk = 0; kk < KK2; ++kk) {
    bf8_t a[2], b[4];
#pragma unroll
    for (int mt = 0; mt < 2; ++mt) {
      const int ra = rowA[mt];
      const int k0 = kk * 32 + g * 8;
      a[mt] = *(const bf8_t*)&mtile[ra * HD + (k0 ^ ((ra & 7) << 3))];
    }
#pragma unroll
    for (int nt = 0; nt < 4; ++nt)
      b[nt] = *(const bf8_t*)(W2p + ((size_t)(kk * 8 + wc * 4 + nt) * 64 + l) * 8);
#pragma unroll
    for (int mt = 0; mt < 2; ++mt)
#pragma unroll
      for (int nt = 0; nt < 4; ++nt)
        acc2[mt][nt] = __builtin_amdgcn_mfma_f32_16x16x32_bf16(a[mt], b[nt], acc2[mt][nt], 0, 0, 0);
  }
  {
    float bn[4];
#pragma unroll
    for (int nt = 0; nt < 4; ++nt) bn[nt] = B2[wc * 64 + nt * 16 + ln];
#pragma unroll
    for (int mt = 0; mt < 2; ++mt)
#pragma unroll
      for (int nt = 0; nt < 4; ++nt) {
        const int col = wc * 64 + nt * 16 + ln;
#pragma unroll
        for (int r = 0; r < 4; ++r) {
          const int row = row0 + mt * 16 + g * 4 + r;
          float* hp = h + (size_t)(n0 + row) * HD + col;
          const float o = *hp + acc2[mt][nt][r] + bn[nt];
          *hp = o;
          hbf_out[(size_t)(n0 + row) * HD + col] = f2bf(o);
        }
      }
  }
}

// ------------------------- generic MFMA head GEMM --------------------------
// out[rb+row, col_off+cb+col] = bf16(relu(A[rb+row,:]@W + bias[cb+col]))
// 64 rows x 128 cols per WG; grid (M/64, N/128).

__global__ __launch_bounds__(256) void gemm_head_kernel(
    const ushort* __restrict__ A, const ushort* __restrict__ Wp,
    const float* __restrict__ bias, ushort* __restrict__ out,
    int lda, int KK, int NTG, int ldo, int col_off) {
  const int t = threadIdx.x;
  const int rb = blockIdx.x * 64;
  const int cb = blockIdx.y * 128;
  const int w = t >> 6, l = t & 63;
  const int wr = w >> 1, wc = w & 1;
  const int g = l >> 4, ln = l & 15;
  const int row0 = wr * 32;
  int rowA[2];
#pragma unroll
  for (int mt = 0; mt < 2; ++mt) rowA[mt] = row0 + mt * 16 + ln;

  const f4_t zf = {0.0f, 0.0f, 0.0f, 0.0f};
  f4_t acc[2][4];
#pragma unroll
  for (int mt = 0; mt < 2; ++mt)
#pragma unroll
    for (int nt = 0; nt < 4; ++nt) acc[mt][nt] = zf;

  const int ntg0 = (cb >> 4) + wc * 4;
  for (int kk = 0; kk < KK; ++kk) {
    bf8_t a[2], b[4];
#pragma unroll
    for (int mt = 0; mt < 2; ++mt)
      a[mt] = *(const bf8_t*)(A + (size_t)(rb + rowA[mt]) * lda + kk * 32 + g * 8);
#pragma unroll
    for (int nt = 0; nt < 4; ++nt)
      b[nt] = *(const bf8_t*)(Wp + ((size_t)(kk * NTG + ntg0 + nt) * 64 + l) * 8);
#pragma unroll
    for (int mt = 0; mt < 2; ++mt)
#pragma unroll
      for (int nt = 0; nt < 4; ++nt)
        acc[mt][nt] = __builtin_amdgcn_mfma_f32_16x16x32_bf16(a[mt], b[nt], acc[mt][nt], 0, 0, 0);
  }
  {
    float bn[4];
#pragma unroll
    for (int nt = 0; nt < 4; ++nt) bn[nt] = bias[cb + wc * 64 + nt * 16 + ln];
#pragma unroll
    for (int mt = 0; mt < 2; ++mt)
#pragma unroll
      for (int nt = 0; nt < 4; ++nt) {
        const int col = cb + wc * 64 + nt * 16 + ln;
#pragma unroll
        for (int r = 0; r < 4; ++r) {
          const int row = row0 + mt * 16 + g * 4 + r;
          const float v = fmaxf(acc[mt][nt][r] + bn[nt], 0.0f);
          out[(size_t)(rb + row) * ldo + col_off + col] = f2bf(v);
        }
      }
  }
}

// ------------------------------ heads --------------------------------------
// mean-pool then emb_out; writes bf16 drug columns into c_in

__global__ __launch_bounds__(128) void pool_kernel(
    const float* __restrict__ h, const float* __restrict__ W,
    const float* __restrict__ B, ushort* __restrict__ c_in) {
  __shared__ float mh[HD];
  const int g = blockIdx.x, t = threadIdx.x;
  float s = 0.0f;
#pragma unroll 4
  for (int n = 0; n < 32; ++n) s += h[((size_t)g * 32 + n) * HD + t];
  mh[t] = s * (1.0f / 32.0f);
  __syncthreads();
  float acc = B[t];
#pragma unroll 4
  for (int k = 0; k < HD; ++k) acc = fmaf(mh[k], W[(size_t)k * HD + t], acc);
  c_in[(size_t)g * (HD + PHD) + t] = f2bf(acc);
}

__global__ __launch_bounds__(256) void logits_kernel(
    const ushort* __restrict__ c, const float* __restrict__ w2,
    const float* __restrict__ b2, float* __restrict__ out) {
  const int t = threadIdx.x;
  const int wave = t >> 6, lane = t & 63;
  const int r = blockIdx.x * 4 + wave;
  const ushort* cp = c + (size_t)r * CHD + lane * 8;
  const float* wp = w2 + lane * 8;
  float s = 0.0f;
#pragma unroll
  for (int j = 0; j < 8; ++j) s = fmaf(bf2f(cp[j]), wp[j], s);
#pragma unroll
  for (int off = 32; off > 0; off >>= 1) s += __shfl_down(s, off, 64);
  if (lane == 0) {
    out[r] = s + b2[0];
    out[NB + r] = 0.0f;
  }
}

// ------------------------------ launch -------------------------------------

extern "C" void kernel_launch(void* const* d_in, const int* in_sizes, int n_in,
                              void* d_out, int out_size, void* d_ws, size_t ws_size,
                              hipStream_t stream) {
  const float* x          = (const float*)d_in[0];
  const float* pos        = (const float*)d_in[1];
  const float* edge_attr  = (const float*)d_in[2];
  const float* pe         = (const float*)d_in[3];
  const int*   edge_index = (const int*)d_in[4];
  const float* emb_in_w   = (const float*)d_in[6];
  const float* emb_in_b   = (const float*)d_in[7];
  const float* emb_out_w  = (const float*)d_in[8];
  const float* emb_out_b  = (const float*)d_in[9];
  const float* edge_w1    = (const float*)d_in[10];
  const float* edge_b1    = (const float*)d_in[11];
  const float* edge_w2    = (const float*)d_in[12];
  const float* edge_b2    = (const float*)d_in[13];
  const float* att_w      = (const float*)d_in[14];
  const float* att_b      = (const float*)d_in[15];
  const float* coord_w1   = (const float*)d_in[16];
  const float* coord_b1   = (const float*)d_in[17];
  const float* coord_w2   = (const float*)d_in[18];
  const float* node_w1    = (const float*)d_in[19];
  const float* node_b1    = (const float*)d_in[20];
  const float* node_w2    = (const float*)d_in[21];
  const float* node_b2    = (const float*)d_in[22];
  const float* prot_w     = (const float*)d_in[23];
  const float* prot_b     = (const float*)d_in[24];
  const float* comb_w1    = (const float*)d_in[25];
  const float* comb_b1    = (const float*)d_in[26];
  const float* comb_w2    = (const float*)d_in[27];
  const float* comb_b2    = (const float*)d_in[28];
  float* out = (float*)d_out;
  (void)in_sizes; (void)n_in; (void)out_size; (void)ws_size;

  char* ws = (char*)d_ws;
  size_t off = 0;
  auto carve = [&](size_t bytes) -> void* {
    void* p = ws + off;
    off += (bytes + 255) & ~(size_t)255;
    return p;
  };
  float*  h       = (float*)carve((size_t)NN * HD * 4);
  ushort* h_bf    = (ushort*)carve((size_t)NN * HD * 2);
  ushort* agg_bf  = (ushort*)carve((size_t)NN * HD * 2);
  ushort* m_bf    = (ushort*)carve((size_t)NE * HD * 2);
  float*  trans   = (float*)carve((size_t)NE * 4 * 4);
  float*  dnb     = (float*)carve((size_t)NE * 4 * 4);
  ushort* extra   = (ushort*)carve((size_t)NE * 32 * 2);
  float*  pos_cur = (float*)carve((size_t)NN * 4 * 4);
  ushort* pe_bf   = (ushort*)carve((size_t)NB * PED * 2);
  ushort* c_in    = (ushort*)carve((size_t)NB * (HD + PHD) * 2);
  ushort* c1      = (ushort*)carve((size_t)NB * CHD * 2);
  const size_t sW1p  = (size_t)KK1 * 8 * 64 * 8;   // ushorts per layer
  const size_t sW2p  = (size_t)KK2 * 8 * 64 * 8;
  const size_t sNW1p = (size_t)KKN1 * 8 * 64 * 8;
  const size_t sPWp  = (size_t)KKP * 32 * 64 * 8;
  const size_t sCWp  = (size_t)KKC * 32 * 64 * 8;
  ushort* W1p     = (ushort*)carve(sW1p * NL * 2);
  ushort* W2p     = (ushort*)carve(sW2p * NL * 2);
  ushort* CW1p    = (ushort*)carve(sW2p * NL * 2);
  ushort* NW1p    = (ushort*)carve(sNW1p * NL * 2);
  ushort* NW2p    = (ushort*)carve(sW2p * NL * 2);
  ushort* PWp     = (ushort*)carve(sPWp * 2);
  ushort* CWp     = (ushort*)carve(sCWp * 2);
  int* deg        = (int*)carve((size_t)NN * 4);
  int* row_ptr    = (int*)carve((size_t)(NN + 1) * 4);
  int* fill_pos   = (int*)carve((size_t)NN * 4);
  int* edge_ids   = (int*)carve((size_t)NE * 4);

  hipMemsetAsync(deg, 0, (size_t)NN * 4, stream);
  hipMemsetAsync(fill_pos, 0, (size_t)NN * 4, stream);

  pos_copy_kernel<<<NN / 256, 256, 0, stream>>>(pos, pos_cur);
  hist_kernel<<<NE / 256, 256, 0, stream>>>(edge_index, deg);
  scan_kernel<<<1, 1024, 0, stream>>>(deg, row_ptr);
  fill_kernel<<<NE / 256, 256, 0, stream>>>(edge_index, row_ptr, fill_pos, edge_ids);

  packw_kernel<<<dim3(18, NL), 256, 0, stream>>>(edge_w1, W1p, 265, HD, KK1,
                                                 (size_t)265 * HD, sW1p);
  packw_kernel<<<dim3(8, NL), 256, 0, stream>>>(edge_w2, W2p, HD, HD, KK2,
                                                (size_t)HD * HD, sW2p);
  packw_kernel<<<dim3(8, NL), 256, 0, stream>>>(coord_w1, CW1p, HD, HD, KK2,
                                                (size_t)HD * HD, sW2p);
  packw_kernel<<<dim3(16, NL), 256, 0, stream>>>(node_w1, NW1p, 2 * HD, HD, KKN1,
                                                 (size_t)2 * HD * HD, sNW1p);
  packw_kernel<<<dim3(8, NL), 256, 0, stream>>>(node_w2, NW2p, HD, HD, KK2,
                                                (size_t)HD * HD, sW2p);
  packw_kernel<<<dim3(320, 1), 256, 0, stream>>>(prot_w, PWp, PED, PHD, KKP, 0, 0);
  packw_kernel<<<dim3(160, 1), 256, 0, stream>>>(comb_w1, CWp, HD + PHD, CHD, KKC, 0, 0);

  cvt_bf_kernel<<<NB * PED / (256 * 8), 256, 0, stream>>>(pe, pe_bf, NB * PED);

  emb_in_kernel<<<NN / 32, 256, 0, stream>>>(x, emb_in_w, emb_in_b, h, h_bf);

  for (int l = 0; l < NL; ++l) {
    geom_kernel<<<NE / 256, 256, 0, stream>>>(pos_cur, edge_attr, edge_index,
                                              dnb, extra);
    edge_mfma_kernel<<<NE / 64, 256, 0, stream>>>(
        h_bf, extra, edge_index, dnb,
        W1p + (size_t)l * sW1p, edge_b1 + (size_t)l * HD,
        W2p + (size_t)l * sW2p, edge_b2 + (size_t)l * HD,
        att_w + (size_t)l * HD, att_b + l,
        CW1p + (size_t)l * sW2p, coord_b1 + (size_t)l * HD,
        coord_w2 + (size_t)l * HD,
        m_bf, trans);
    gather_kernel<<<NN / 4, 256, 0, stream>>>(m_bf, trans, row_ptr, edge_ids,
                                              agg_bf, pos_cur);
    node_mfma_kernel<<<NN / 64, 256, 0, stream>>>(
        h, h_bf, agg_bf,
        NW1p + (size_t)l * sNW1p, node_b1 + (size_t)l * HD,
        NW2p + (size_t)l * sW2p, node_b2 + (size_t)l * HD, h_bf);
  }

  pool_kernel<<<NB, 128, 0, stream>>>(h, emb_out_w, emb_out_b, c_in);
  // prot: relu(pe @ prot_w + b) -> c_in cols 128..639
  gemm_head_kernel<<<dim3(NB / 64, PHD / 128), 256, 0, stream>>>(
      pe_bf, PWp, prot_b, c_in, PED, KKP, PHD / 16, HD + PHD, HD);
  // comb1: relu(c_in @ comb_w1 + b) -> c1
  gemm_head_kernel<<<dim3(NB / 64, CHD / 128), 256, 0, stream>>>(
      c_in, CWp, comb_b1, c1, HD + PHD, KKC, CHD / 16, CHD, 0);
  logits_kernel<<<NB / 4, 256, 0, stream>>>(c1, comb_w2, comb_b2, out);
}

// Round 4
// 1025.899 us; speedup vs baseline: 3.6914x; 1.0665x over previous
//
#include <hip/hip_runtime.h>
#include <math.h>

// ---------------------------------------------------------------------------
// DTIModel (EGNN + protein head) forward.
// R4: transposed MFMA edge/node kernels (weights as M-operand -> D rows =
// features, cols = edges/nodes). LDS epilogue writes become ds_write_b64,
// reductions 2-level; CSR-ordered edges make gather fully sequential.
// ---------------------------------------------------------------------------

static constexpr int NN  = 65536;   // nodes
static constexpr int NE  = 262144;  // edges
static constexpr int NB  = 2048;    // graphs
static constexpr int NDF = 32;      // node feat in
static constexpr int HD  = 128;     // hidden
static constexpr int NL  = 4;       // egnn layers
static constexpr int PED = 1280;    // protein embed
static constexpr int PHD = 512;     // protein hidden
static constexpr int CHD = 512;     // combined hidden
static constexpr float EPSV = 1e-8f;

static constexpr int KK1 = 9;  // ceil(265/32) edge GEMM1
static constexpr int KK2 = 4;  // 128/32
static constexpr int KKN1 = 8; // 256/32 node GEMM1
static constexpr int KKP = 40; // 1280/32 prot
static constexpr int KKC = 20; // 640/32 comb1

static constexpr int ES = 36;  // f32 LDS row stride (emb_in)

typedef __attribute__((ext_vector_type(8))) short bf8_t;
typedef __attribute__((ext_vector_type(4))) float f4_t;

__device__ __forceinline__ float sigmoid_f(float x) {
  return __fdividef(1.0f, 1.0f + __expf(-x));
}
__device__ __forceinline__ float silu_f(float x) { return x * sigmoid_f(x); }

__device__ __forceinline__ ushort f2bf(float f) {  // RNE
  unsigned u = __float_as_uint(f);
  u += 0x7FFFu + ((u >> 16) & 1u);
  return (ushort)(u >> 16);
}
__device__ __forceinline__ float bf2f(ushort h) {
  return __uint_as_float(((unsigned)h) << 16);
}
__device__ __forceinline__ unsigned pk2bf(float a, float b) {
  return (unsigned)f2bf(a) | ((unsigned)f2bf(b) << 16);
}

__device__ __forceinline__ void fma44(float (&acc)[4][4], const float4 a, const float4 w) {
  const float av[4] = {a.x, a.y, a.z, a.w};
  const float wv[4] = {w.x, w.y, w.z, w.w};
#pragma unroll
  for (int i = 0; i < 4; ++i)
#pragma unroll
    for (int j = 0; j < 4; ++j) acc[i][j] = fmaf(av[i], wv[j], acc[i][j]);
}

// --------------------------- CSR construction ------------------------------

__global__ void hist_kernel(const int* __restrict__ ei, int* __restrict__ deg) {
  const int e = blockIdx.x * 256 + threadIdx.x;
  if (e < NE) atomicAdd(&deg[ei[e]], 1);
}

__global__ __launch_bounds__(1024) void scan_kernel(const int* __restrict__ deg,
                                                    int* __restrict__ row_ptr) {
  __shared__ int wsums[16];
  __shared__ int carry_s;
  const int t = threadIdx.x;
  const int lane = t & 63, wave = t >> 6;
  if (t == 0) { carry_s = 0; row_ptr[0] = 0; }
  __syncthreads();
  for (int c = 0; c < NN / 1024; ++c) {
    const int i = c * 1024 + t;
    int incl = deg[i];
#pragma unroll
    for (int d = 1; d < 64; d <<= 1) {
      const int u = __shfl_up(incl, d, 64);
      if (lane >= d) incl += u;
    }
    if (lane == 63) wsums[wave] = incl;
    __syncthreads();
    if (t == 0) {
      int a = carry_s;
#pragma unroll
      for (int w = 0; w < 16; ++w) { const int tmp = wsums[w]; wsums[w] = a; a += tmp; }
      carry_s = a;
    }
    __syncthreads();
    row_ptr[i + 1] = wsums[wave] + incl;
    __syncthreads();
  }
}

__global__ void fill_kernel(const int* __restrict__ ei, const int* __restrict__ row_ptr,
                            int* __restrict__ fill_pos, int* __restrict__ edge_ids) {
  const int e = blockIdx.x * 256 + threadIdx.x;
  if (e < NE) {
    const int n = ei[e];
    const int s = atomicAdd(&fill_pos[n], 1);
    edge_ids[row_ptr[n] + s] = e;
  }
}

// CSR-position arrays: rowp/colp/eap[i] for CSR position i (edge edge_ids[i])
__global__ void perm_kernel(const int* __restrict__ ei, const int* __restrict__ edge_ids,
                            const float* __restrict__ edge_attr,
                            int* __restrict__ rowp, int* __restrict__ colp,
                            float* __restrict__ eap) {
  const int i = blockIdx.x * 256 + threadIdx.x;
  if (i >= NE) return;
  const int e = edge_ids[i];
  rowp[i] = ei[e];
  colp[i] = ei[NE + e];
  const float4 a = *(const float4*)(edge_attr + (size_t)e * 8);
  const float4 b = *(const float4*)(edge_attr + (size_t)e * 8 + 4);
  *(float4*)(eap + (size_t)i * 8) = a;
  *(float4*)(eap + (size_t)i * 8 + 4) = b;
}

__global__ void pos_copy_kernel(const float* __restrict__ pos, float* __restrict__ pc) {
  const int n = blockIdx.x * 256 + threadIdx.x;
  if (n < NN) {
    const float4 v = make_float4(pos[(size_t)n * 3 + 0], pos[(size_t)n * 3 + 1],
                                 pos[(size_t)n * 3 + 2], 0.0f);
    *(float4*)(pc + (size_t)n * 4) = v;
  }
}

// ------------------------- weight fragment packing -------------------------
// Wp[((kk*NTG + ntg)*64 + l)*8 + e] = bf16(W[k][n]), k = kk*32+(l>>4)*8+e,
// n = ntg*16+(l&15). Used as either operand (A/B layouts symmetric).

__global__ __launch_bounds__(256) void packw_kernel(
    const float* __restrict__ W, ushort* __restrict__ Wp,
    int K, int N, int KK, size_t sW, size_t sWp) {
  const int layer = blockIdx.y;
  const int NTG = N >> 4;
  const int i = blockIdx.x * 256 + threadIdx.x;
  if (i >= KK * NTG * 64) return;
  const int l = i & 63;
  const int q = i >> 6;
  const int ntg = q % NTG;
  const int kk = q / NTG;
  const int k0 = kk * 32 + ((l >> 4) * 8);
  const int n = ntg * 16 + (l & 15);
  const float* w = W + layer * sW;
  unsigned ww[4];
#pragma unroll
  for (int p = 0; p < 4; ++p) {
    const int ka = k0 + p * 2, kb = ka + 1;
    const unsigned lo = (ka < K) ? f2bf(w[(size_t)ka * N + n]) : 0;
    const unsigned hi = (kb < K) ? f2bf(w[(size_t)kb * N + n]) : 0;
    ww[p] = lo | (hi << 16);
  }
  *(uint4*)(Wp + layer * sWp + (size_t)i * 8) = make_uint4(ww[0], ww[1], ww[2], ww[3]);
}

// f32 -> bf16 bulk convert
__global__ __launch_bounds__(256) void cvt_bf_kernel(const float* __restrict__ in,
                                                     ushort* __restrict__ out, int n) {
  const int i = blockIdx.x * 256 + threadIdx.x;
  if (i * 8 >= n) return;
  const float4 v0 = *(const float4*)(in + (size_t)i * 8);
  const float4 v1 = *(const float4*)(in + (size_t)i * 8 + 4);
  *(uint4*)(out + (size_t)i * 8) =
      make_uint4(pk2bf(v0.x, v0.y), pk2bf(v0.z, v0.w), pk2bf(v1.x, v1.y), pk2bf(v1.z, v1.w));
}

// ------------------------- per-layer edge geometry -------------------------

__global__ __launch_bounds__(256) void geom_kernel(
    const float* __restrict__ pos_cur, const float* __restrict__ eap,
    const int* __restrict__ rowp, const int* __restrict__ colp,
    float* __restrict__ dnb, ushort* __restrict__ extra) {
  const int i = blockIdx.x * 256 + threadIdx.x;
  if (i >= NE) return;
  const int r = rowp[i], c = colp[i];
  const float4 pr = *(const float4*)(pos_cur + (size_t)r * 4);
  const float4 pc = *(const float4*)(pos_cur + (size_t)c * 4);
  const float dx = pr.x - pc.x, dy = pr.y - pc.y, dz = pr.z - pc.z;
  const float radial = dx * dx + dy * dy + dz * dz;
  const float inv = 1.0f / (sqrtf(radial) + EPSV);
  *(float4*)(dnb + (size_t)i * 4) = make_float4(dx * inv, dy * inv, dz * inv, 0.0f);
  const float4 ea0 = *(const float4*)(eap + (size_t)i * 8);
  const float4 ea1 = *(const float4*)(eap + (size_t)i * 8 + 4);
  ushort* dst = extra + (size_t)i * 32;
  *(uint4*)(dst) = make_uint4(pk2bf(radial, ea0.x), pk2bf(ea0.y, ea0.z),
                              pk2bf(ea0.w, ea1.x), pk2bf(ea1.y, ea1.z));
  *(uint4*)(dst + 8)  = make_uint4((unsigned)f2bf(ea1.w), 0, 0, 0);
  *(uint4*)(dst + 16) = make_uint4(0, 0, 0, 0);
  *(uint4*)(dst + 24) = make_uint4(0, 0, 0, 0);
}

// ------------------------------- emb_in ------------------------------------

__global__ __launch_bounds__(256) void emb_in_kernel(
    const float* __restrict__ x, const float* __restrict__ W,
    const float* __restrict__ B, float* __restrict__ h, ushort* __restrict__ hbf) {
  __shared__ float xs[NDF * ES];
  const int t = threadIdx.x;
  const int n0 = blockIdx.x * 32;
  {
    const int r = t >> 3;
    const int kq = (t & 7) * 4;
    const float4 v = *(const float4*)(x + (size_t)(n0 + r) * NDF + kq);
    xs[(kq + 0) * ES + r] = v.x;
    xs[(kq + 1) * ES + r] = v.y;
    xs[(kq + 2) * ES + r] = v.z;
    xs[(kq + 3) * ES + r] = v.w;
  }
  __syncthreads();
  const int eg = t & 7, fg = t >> 3;
  float acc[4][4] = {};
  const float* wp = W + fg * 4;
#pragma unroll
  for (int k = 0; k < NDF; ++k) {
    const float4 a = *(const float4*)&xs[k * ES + eg * 4];
    const float4 w = *(const float4*)(wp + (size_t)k * HD);
    fma44(acc, a, w);
  }
  const float4 bv = *(const float4*)(B + fg * 4);
  const float bb[4] = {bv.x, bv.y, bv.z, bv.w};
#pragma unroll
  for (int i = 0; i < 4; ++i) {
    const float4 o = make_float4(acc[i][0] + bb[0], acc[i][1] + bb[1],
                                 acc[i][2] + bb[2], acc[i][3] + bb[3]);
    *(float4*)(h + (size_t)(n0 + eg * 4 + i) * HD + fg * 4) = o;
    *(uint2*)(hbf + (size_t)(n0 + eg * 4 + i) * HD + fg * 4) =
        make_uint2(pk2bf(o.x, o.y), pk2bf(o.z, o.w));
  }
}

// --------------------- transposed MFMA edge kernel -------------------------
// D rows = features (M), cols = edges (N). 4 waves: (wn,we) in 2x2;
// per wave 64 feats x 32 edges as 4(mt) x 2(et) fragments. LDS m-tile is
// [edge][feat ^ swz]; epilogue writes ds_write_b64, A-reads ds_read_b128.

__global__ __launch_bounds__(256) void edge_mfma_kernel(
    const ushort* __restrict__ hbf, const ushort* __restrict__ extra,
    const int* __restrict__ rowp, const int* __restrict__ colp,
    const float* __restrict__ dnb,
    const ushort* __restrict__ W1p, const float* __restrict__ B1,
    const ushort* __restrict__ W2p, const float* __restrict__ B2,
    const float* __restrict__ AW, const float* __restrict__ AB,
    const ushort* __restrict__ CW1p, const float* __restrict__ CB1,
    const float* __restrict__ CW2,
    ushort* __restrict__ m_bf, float* __restrict__ trans_out) {
  __shared__ ushort mtileT[64 * 128];  // [edge][feat^swz], 16 KB
  __shared__ int ridx[64], cidx[64];
  __shared__ float redbuf[2][64];
  __shared__ float gates[64];

  const int t = threadIdx.x;
  const int e0 = blockIdx.x * 64;
  if (t < 64) {
    ridx[t] = rowp[e0 + t];
    cidx[t] = colp[e0 + t];
  }
  __syncthreads();

  const int w = t >> 6, l = t & 63;
  const int wn = w & 1, we = w >> 1;
  const int g = l >> 4, ln = l & 15;
  const int nb = wn * 64;  // feature base (M)
  const int eb = we * 32;  // edge base (N)

  int je[2], er[2], ec[2], swz[2];
#pragma unroll
  for (int et = 0; et < 2; ++et) {
    je[et] = eb + et * 16 + ln;
    er[et] = ridx[je[et]];
    ec[et] = cidx[je[et]];
    swz[et] = (je[et] & 7) << 3;
  }

  const f4_t zf = {0.0f, 0.0f, 0.0f, 0.0f};
  f4_t acc[4][2];
#pragma unroll
  for (int mt = 0; mt < 4; ++mt)
#pragma unroll
    for (int et = 0; et < 2; ++et) acc[mt][et] = zf;

  // ---- GEMM1: m1T[n][e] = sum_k W1[k][n] * e_in[e][k], K=288
#pragma unroll
  for (int kk = 0; kk < KK1; ++kk) {
    bf8_t aw[4], be[2];
#pragma unroll
    for (int mt = 0; mt < 4; ++mt)
      aw[mt] = *(const bf8_t*)(W1p + ((size_t)(kk * 8 + wn * 4 + mt) * 64 + l) * 8);
#pragma unroll
    for (int et = 0; et < 2; ++et) {
      if (kk < 8) {
        const int idx = (kk < 4) ? er[et] : ec[et];
        be[et] = *(const bf8_t*)(hbf + (size_t)idx * HD + (kk & 3) * 32 + g * 8);
      } else {
        be[et] = *(const bf8_t*)(extra + (size_t)(e0 + je[et]) * 32 + g * 8);
      }
    }
#pragma unroll
    for (int mt = 0; mt < 4; ++mt)
#pragma unroll
      for (int et = 0; et < 2; ++et)
        acc[mt][et] = __builtin_amdgcn_mfma_f32_16x16x32_bf16(aw[mt], be[et], acc[mt][et], 0, 0, 0);
  }

  // m1 = silu(acc + b1) -> LDS (b64 per fragment)
  {
#pragma unroll
    for (int mt = 0; mt < 4; ++mt) {
      const int n0 = nb + mt * 16 + g * 4;
      const float4 bv = *(const float4*)(B1 + n0);
#pragma unroll
      for (int et = 0; et < 2; ++et) {
        const unsigned lo = pk2bf(silu_f(acc[mt][et][0] + bv.x), silu_f(acc[mt][et][1] + bv.y));
        const unsigned hi = pk2bf(silu_f(acc[mt][et][2] + bv.z), silu_f(acc[mt][et][3] + bv.w));
        *(uint2*)&mtileT[je[et] * HD + (n0 ^ swz[et])] = make_uint2(lo, hi);
      }
    }
  }
  __syncthreads();

  // ---- GEMM2: m2T = W2T @ m1T, K=128 (+ attention gate)
  f4_t acc2[4][2];
#pragma unroll
  for (int mt = 0; mt < 4; ++mt)
#pragma unroll
    for (int et = 0; et < 2; ++et) acc2[mt][et] = zf;
#pragma unroll
  for (int kk = 0; kk < KK2; ++kk) {
    bf8_t aw[4], be[2];
#pragma unroll
    for (int mt = 0; mt < 4; ++mt)
      aw[mt] = *(const bf8_t*)(W2p + ((size_t)(kk * 8 + wn * 4 + mt) * 64 + l) * 8);
    const int nk = kk * 32 + g * 8;
#pragma unroll
    for (int et = 0; et < 2; ++et)
      be[et] = *(const bf8_t*)&mtileT[je[et] * HD + (nk ^ swz[et])];
#pragma unroll
    for (int mt = 0; mt < 4; ++mt)
#pragma unroll
      for (int et = 0; et < 2; ++et)
        acc2[mt][et] = __builtin_amdgcn_mfma_f32_16x16x32_bf16(aw[mt], be[et], acc2[mt][et], 0, 0, 0);
  }

  float m2v[4][2][4];
  {
    float p[2] = {0.0f, 0.0f};
#pragma unroll
    for (int mt = 0; mt < 4; ++mt) {
      const int n0 = nb + mt * 16 + g * 4;
      const float4 bv = *(const float4*)(B2 + n0);
      const float4 av = *(const float4*)(AW + n0);
      const float bb[4] = {bv.x, bv.y, bv.z, bv.w};
      const float aa[4] = {av.x, av.y, av.z, av.w};
#pragma unroll
      for (int et = 0; et < 2; ++et)
#pragma unroll
        for (int r = 0; r < 4; ++r) {
          const float v = silu_f(acc2[mt][et][r] + bb[r]);
          m2v[mt][et][r] = v;
          p[et] = fmaf(v, aa[r], p[et]);
        }
    }
#pragma unroll
    for (int et = 0; et < 2; ++et) {
      p[et] += __shfl_xor(p[et], 16, 64);
      p[et] += __shfl_xor(p[et], 32, 64);
    }
    if (l < 16) {
#pragma unroll
      for (int et = 0; et < 2; ++et) redbuf[wn][eb + et * 16 + l] = p[et];
    }
  }
  __syncthreads();
  if (t < 64) gates[t] = sigmoid_f(redbuf[0][t] + redbuf[1][t] + AB[0]);
  __syncthreads();

  // gated m -> LDS
  {
    float grow[2];
#pragma unroll
    for (int et = 0; et < 2; ++et) grow[et] = gates[je[et]];
#pragma unroll
    for (int mt = 0; mt < 4; ++mt) {
      const int n0 = nb + mt * 16 + g * 4;
#pragma unroll
      for (int et = 0; et < 2; ++et) {
        const unsigned lo = pk2bf(m2v[mt][et][0] * grow[et], m2v[mt][et][1] * grow[et]);
        const unsigned hi = pk2bf(m2v[mt][et][2] * grow[et], m2v[mt][et][3] * grow[et]);
        *(uint2*)&mtileT[je[et] * HD + (n0 ^ swz[et])] = make_uint2(lo, hi);
      }
    }
  }
  __syncthreads();

  // ---- GEMM3: t2T = CW1T @ mT, K=128; coord scalar = tanh(t2 . cw2)
  f4_t acc3[4][2];
#pragma unroll
  for (int mt = 0; mt < 4; ++mt)
#pragma unroll
    for (int et = 0; et < 2; ++et) acc3[mt][et] = zf;
#pragma unroll
  for (int kk = 0; kk < KK2; ++kk) {
    bf8_t aw[4], be[2];
#pragma unroll
    for (int mt = 0; mt < 4; ++mt)
      aw[mt] = *(const bf8_t*)(CW1p + ((size_t)(kk * 8 + wn * 4 + mt) * 64 + l) * 8);
    const int nk = kk * 32 + g * 8;
#pragma unroll
    for (int et = 0; et < 2; ++et)
      be[et] = *(const bf8_t*)&mtileT[je[et] * HD + (nk ^ swz[et])];
#pragma unroll
    for (int mt = 0; mt < 4; ++mt)
#pragma unroll
      for (int et = 0; et < 2; ++et)
        acc3[mt][et] = __builtin_amdgcn_mfma_f32_16x16x32_bf16(aw[mt], be[et], acc3[mt][et], 0, 0, 0);
  }
  {
    float q[2] = {0.0f, 0.0f};
#pragma unroll
    for (int mt = 0; mt < 4; ++mt) {
      const int n0 = nb + mt * 16 + g * 4;
      const float4 bv = *(const float4*)(CB1 + n0);
      const float4 cv = *(const float4*)(CW2 + n0);
      const float bb[4] = {bv.x, bv.y, bv.z, bv.w};
      const float cc[4] = {cv.x, cv.y, cv.z, cv.w};
#pragma unroll
      for (int et = 0; et < 2; ++et)
#pragma unroll
        for (int r = 0; r < 4; ++r)
          q[et] = fmaf(silu_f(acc3[mt][et][r] + bb[r]), cc[r], q[et]);
    }
#pragma unroll
    for (int et = 0; et < 2; ++et) {
      q[et] += __shfl_xor(q[et], 16, 64);
      q[et] += __shfl_xor(q[et], 32, 64);
    }
    if (l < 16) {
#pragma unroll
      for (int et = 0; et < 2; ++et) redbuf[wn][eb + et * 16 + l] = q[et];
    }
  }
  __syncthreads();
  if (t < 64) {
    const float s = tanhf(redbuf[0][t] + redbuf[1][t]);
    const f4_t dn = *(const f4_t*)(dnb + (size_t)(e0 + t) * 4);
    const f4_t tr = dn * s;
    *(f4_t*)(trans_out + (size_t)(e0 + t) * 4) = tr;
  }

  // bulk copy gated-m LDS tile -> global m_bf (de-swizzle)
#pragma unroll
  for (int it = 0; it < 4; ++it) {
    const int i = it * 256 + t;
    const int row = i >> 4;
    const int c8 = (i & 15) * 8;
    const uint4 v = *(const uint4*)&mtileT[row * HD + (c8 ^ ((row & 7) << 3))];
    *(uint4*)(m_bf + (size_t)(e0 + row) * HD + c8) = v;
  }
}

// ------------------------ gather (segment sums) ----------------------------
// CSR-ordered m rows: fully sequential stream. One wave per node.

__global__ __launch_bounds__(256) void gather_kernel(
    const ushort* __restrict__ m_bf, const float* __restrict__ trans,
    const int* __restrict__ row_ptr,
    ushort* __restrict__ agg_bf, float* __restrict__ pos_cur) {
  const int t = threadIdx.x;
  const int wave = t >> 6, lane = t & 63;
  const int n = blockIdx.x * 4 + wave;
  const int s = row_ptr[n], e_end = row_ptr[n + 1];
  float a0 = 0.0f, a1 = 0.0f, ta = 0.0f;
  for (int i = s; i < e_end; ++i) {
    const ushort2 v = *(const ushort2*)(m_bf + (size_t)i * HD + lane * 2);
    a0 += bf2f(v.x);
    a1 += bf2f(v.y);
    if (lane < 4) ta += trans[(size_t)i * 4 + lane];
  }
  ushort2 ab;
  ab.x = f2bf(a0);
  ab.y = f2bf(a1);
  *(ushort2*)(agg_bf + (size_t)n * HD + lane * 2) = ab;
  if (lane < 3) {
    const int dg = e_end - s;
    pos_cur[(size_t)n * 4 + lane] += ta / (float)(dg > 0 ? dg : 1);
  }
}

// --------------------- transposed MFMA node kernel -------------------------
// Same scheme: D rows = features, cols = nodes. Residual epilogue is
// float4 h RMW + packed bf16 store (64B segments).

__global__ __launch_bounds__(256) void node_mfma_kernel(
    float* __restrict__ h, const ushort* __restrict__ hbf,
    const ushort* __restrict__ agg_bf,
    const ushort* __restrict__ W1p, const float* __restrict__ B1,
    const ushort* __restrict__ W2p, const float* __restrict__ B2,
    ushort* __restrict__ hbf_out) {
  __shared__ ushort mtileT[64 * 128];
  const int t = threadIdx.x;
  const int n0blk = blockIdx.x * 64;
  const int w = t >> 6, l = t & 63;
  const int wn = w & 1, we = w >> 1;
  const int g = l >> 4, ln = l & 15;
  const int nb = wn * 64;
  const int eb = we * 32;

  int jn[2], swz[2];
#pragma unroll
  for (int et = 0; et < 2; ++et) {
    jn[et] = eb + et * 16 + ln;
    swz[et] = (jn[et] & 7) << 3;
  }

  const f4_t zf = {0.0f, 0.0f, 0.0f, 0.0f};
  f4_t acc[4][2];
#pragma unroll
  for (int mt = 0; mt < 4; ++mt)
#pragma unroll
    for (int et = 0; et < 2; ++et) acc[mt][et] = zf;

  // GEMM1: K=256 ([h|agg])
#pragma unroll
  for (int kk = 0; kk < KKN1; ++kk) {
    bf8_t aw[4], be[2];
#pragma unroll
    for (int mt = 0; mt < 4; ++mt)
      aw[mt] = *(const bf8_t*)(W1p + ((size_t)(kk * 8 + wn * 4 + mt) * 64 + l) * 8);
#pragma unroll
    for (int et = 0; et < 2; ++et) {
      const size_t base = (size_t)(n0blk + jn[et]) * HD + (kk & 3) * 32 + g * 8;
      be[et] = (kk < 4) ? *(const bf8_t*)(hbf + base) : *(const bf8_t*)(agg_bf + base);
    }
#pragma unroll
    for (int mt = 0; mt < 4; ++mt)
#pragma unroll
      for (int et = 0; et < 2; ++et)
        acc[mt][et] = __builtin_amdgcn_mfma_f32_16x16x32_bf16(aw[mt], be[et], acc[mt][et], 0, 0, 0);
  }
  {
#pragma unroll
    for (int mt = 0; mt < 4; ++mt) {
      const int n0 = nb + mt * 16 + g * 4;
      const float4 bv = *(const float4*)(B1 + n0);
#pragma unroll
      for (int et = 0; et < 2; ++et) {
        const unsigned lo = pk2bf(silu_f(acc[mt][et][0] + bv.x), silu_f(acc[mt][et][1] + bv.y));
        const unsigned hi = pk2bf(silu_f(acc[mt][et][2] + bv.z), silu_f(acc[mt][et][3] + bv.w));
        *(uint2*)&mtileT[jn[et] * HD + (n0 ^ swz[et])] = make_uint2(lo, hi);
      }
    }
  }
  __syncthreads();

  // GEMM2: K=128; h += out + b2
  f4_t acc2[4][2];
#pragma unroll
  for (int mt = 0; mt < 4; ++mt)
#pragma unroll
    for (int et = 0; et < 2; ++et) acc2[mt][et] = zf;
#pragma unroll
  for (int kk = 0; kk < KK2; ++kk) {
    bf8_t aw[4], be[2];
#pragma unroll
    for (int mt = 0; mt < 4; ++mt)
      aw[mt] = *(const bf8_t*)(W2p + ((size_t)(kk * 8 + wn * 4 + mt) * 64 + l) * 8);
    const int nk = kk * 32 + g * 8;
#pragma unroll
    for (int et = 0; et < 2; ++et)
      be[et] = *(const bf8_t*)&mtileT[jn[et] * HD + (nk ^ swz[et])];
#pragma unroll
    for (int mt = 0; mt < 4; ++mt)
#pragma unroll
      for (int et = 0; et < 2; ++et)
        acc2[mt][et] = __builtin_amdgcn_mfma_f32_16x16x32_bf16(aw[mt], be[et], acc2[mt][et], 0, 0, 0);
  }
  {
#pragma unroll
    for (int mt = 0; mt < 4; ++mt) {
      const int n0 = nb + mt * 16 + g * 4;
      const float4 bv = *(const float4*)(B2 + n0);
#pragma unroll
      for (int et = 0; et < 2; ++et) {
        float* hp = h + (size_t)(n0blk + jn[et]) * HD + n0;
        const float4 old = *(const float4*)hp;
        float4 o;
        o.x = old.x + acc2[mt][et][0] + bv.x;
        o.y = old.y + acc2[mt][et][1] + bv.y;
        o.z = old.z + acc2[mt][et][2] + bv.z;
        o.w = old.w + acc2[mt][et][3] + bv.w;
        *(float4*)hp = o;
        *(uint2*)(hbf_out + (size_t)(n0blk + jn[et]) * HD + n0) =
            make_uint2(pk2bf(o.x, o.y), pk2bf(o.z, o.w));
      }
    }
  }
}

// ------------------------- generic MFMA head GEMM --------------------------

__global__ __launch_bounds__(256) void gemm_head_kernel(
    const ushort* __restrict__ A, const ushort* __restrict__ Wp,
    const float* __restrict__ bias, ushort* __restrict__ out,
    int lda, int KK, int NTG, int ldo, int col_off) {
  const int t = threadIdx.x;
  const int rb = blockIdx.x * 64;
  const int cb = blockIdx.y * 128;
  const int w = t >> 6, l = t & 63;
  const int wr = w >> 1, wc = w & 1;
  const int g = l >> 4, ln = l & 15;
  const int row0 = wr * 32;
  int rowA[2];
#pragma unroll
  for (int mt = 0; mt < 2; ++mt) rowA[mt] = row0 + mt * 16 + ln;

  const f4_t zf = {0.0f, 0.0f, 0.0f, 0.0f};
  f4_t acc[2][4];
#pragma unroll
  for (int mt = 0; mt < 2; ++mt)
#pragma unroll
    for (int nt = 0; nt < 4; ++nt) acc[mt][nt] = zf;

  const int ntg0 = (cb >> 4) + wc * 4;
  for (int kk = 0; kk < KK; ++kk) {
    bf8_t a[2], b[4];
#pragma unroll
    for (int mt = 0; mt < 2; ++mt)
      a[mt] = *(const bf8_t*)(A + (size_t)(rb + rowA[mt]) * lda + kk * 32 + g * 8);
#pragma unroll
    for (int nt = 0; nt < 4; ++nt)
      b[nt] = *(const bf8_t*)(Wp + ((size_t)(kk * NTG + ntg0 + nt) * 64 + l) * 8);
#pragma unroll
    for (int mt = 0; mt < 2; ++mt)
#pragma unroll
      for (int nt = 0; nt < 4; ++nt)
        acc[mt][nt] = __builtin_amdgcn_mfma_f32_16x16x32_bf16(a[mt], b[nt], acc[mt][nt], 0, 0, 0);
  }
  {
    float bn[4];
#pragma unroll
    for (int nt = 0; nt < 4; ++nt) bn[nt] = bias[cb + wc * 64 + nt * 16 + ln];
#pragma unroll
    for (int mt = 0; mt < 2; ++mt)
#pragma unroll
      for (int nt = 0; nt < 4; ++nt) {
        const int col = cb + wc * 64 + nt * 16 + ln;
#pragma unroll
        for (int r = 0; r < 4; ++r) {
          const int row = row0 + mt * 16 + g * 4 + r;
          const float v = fmaxf(acc[mt][nt][r] + bn[nt], 0.0f);
          out[(size_t)(rb + row) * ldo + col_off + col] = f2bf(v);
        }
      }
  }
}

// ------------------------------ heads --------------------------------------

__global__ __launch_bounds__(128) void pool_kernel(
    const float* __restrict__ h, const float* __restrict__ W,
    const float* __restrict__ B, ushort* __restrict__ c_in) {
  __shared__ float mh[HD];
  const int g = blockIdx.x, t = threadIdx.x;
  float s = 0.0f;
#pragma unroll 4
  for (int n = 0; n < 32; ++n) s += h[((size_t)g * 32 + n) * HD + t];
  mh[t] = s * (1.0f / 32.0f);
  __syncthreads();
  float acc = B[t];
#pragma unroll 4
  for (int k = 0; k < HD; ++k) acc = fmaf(mh[k], W[(size_t)k * HD + t], acc);
  c_in[(size_t)g * (HD + PHD) + t] = f2bf(acc);
}

__global__ __launch_bounds__(256) void logits_kernel(
    const ushort* __restrict__ c, const float* __restrict__ w2,
    const float* __restrict__ b2, float* __restrict__ out) {
  const int t = threadIdx.x;
  const int wave = t >> 6, lane = t & 63;
  const int r = blockIdx.x * 4 + wave;
  const ushort* cp = c + (size_t)r * CHD + lane * 8;
  const float* wp = w2 + lane * 8;
  float s = 0.0f;
#pragma unroll
  for (int j = 0; j < 8; ++j) s = fmaf(bf2f(cp[j]), wp[j], s);
#pragma unroll
  for (int off = 32; off > 0; off >>= 1) s += __shfl_down(s, off, 64);
  if (lane == 0) {
    out[r] = s + b2[0];
    out[NB + r] = 0.0f;
  }
}

// ------------------------------ launch -------------------------------------

extern "C" void kernel_launch(void* const* d_in, const int* in_sizes, int n_in,
                              void* d_out, int out_size, void* d_ws, size_t ws_size,
                              hipStream_t stream) {
  const float* x          = (const float*)d_in[0];
  const float* pos        = (const float*)d_in[1];
  const float* edge_attr  = (const float*)d_in[2];
  const float* pe         = (const float*)d_in[3];
  const int*   edge_index = (const int*)d_in[4];
  const float* emb_in_w   = (const float*)d_in[6];
  const float* emb_in_b   = (const float*)d_in[7];
  const float* emb_out_w  = (const float*)d_in[8];
  const float* emb_out_b  = (const float*)d_in[9];
  const float* edge_w1    = (const float*)d_in[10];
  const float* edge_b1    = (const float*)d_in[11];
  const float* edge_w2    = (const float*)d_in[12];
  const float* edge_b2    = (const float*)d_in[13];
  const float* att_w      = (const float*)d_in[14];
  const float* att_b      = (const float*)d_in[15];
  const float* coord_w1   = (const float*)d_in[16];
  const float* coord_b1   = (const float*)d_in[17];
  const float* coord_w2   = (const float*)d_in[18];
  const float* node_w1    = (const float*)d_in[19];
  const float* node_b1    = (const float*)d_in[20];
  const float* node_w2    = (const float*)d_in[21];
  const float* node_b2    = (const float*)d_in[22];
  const float* prot_w     = (const float*)d_in[23];
  const float* prot_b     = (const float*)d_in[24];
  const float* comb_w1    = (const float*)d_in[25];
  const float* comb_b1    = (const float*)d_in[26];
  const float* comb_w2    = (const float*)d_in[27];
  const float* comb_b2    = (const float*)d_in[28];
  float* out = (float*)d_out;
  (void)in_sizes; (void)n_in; (void)out_size; (void)ws_size;

  char* ws = (char*)d_ws;
  size_t off = 0;
  auto carve = [&](size_t bytes) -> void* {
    void* p = ws + off;
    off += (bytes + 255) & ~(size_t)255;
    return p;
  };
  float*  h       = (float*)carve((size_t)NN * HD * 4);
  ushort* h_bf    = (ushort*)carve((size_t)NN * HD * 2);
  ushort* agg_bf  = (ushort*)carve((size_t)NN * HD * 2);
  ushort* m_bf    = (ushort*)carve((size_t)NE * HD * 2);
  float*  trans   = (float*)carve((size_t)NE * 4 * 4);
  float*  dnb     = (float*)carve((size_t)NE * 4 * 4);
  ushort* extra   = (ushort*)carve((size_t)NE * 32 * 2);
  float*  eap     = (float*)carve((size_t)NE * 8 * 4);
  float*  pos_cur = (float*)carve((size_t)NN * 4 * 4);
  ushort* pe_bf   = (ushort*)carve((size_t)NB * PED * 2);
  ushort* c_in    = (ushort*)carve((size_t)NB * (HD + PHD) * 2);
  ushort* c1      = (ushort*)carve((size_t)NB * CHD * 2);
  const size_t sW1p  = (size_t)KK1 * 8 * 64 * 8;
  const size_t sW2p  = (size_t)KK2 * 8 * 64 * 8;
  const size_t sNW1p = (size_t)KKN1 * 8 * 64 * 8;
  const size_t sPWp  = (size_t)KKP * 32 * 64 * 8;
  const size_t sCWp  = (size_t)KKC * 32 * 64 * 8;
  ushort* W1p     = (ushort*)carve(sW1p * NL * 2);
  ushort* W2p     = (ushort*)carve(sW2p * NL * 2);
  ushort* CW1p    = (ushort*)carve(sW2p * NL * 2);
  ushort* NW1p    = (ushort*)carve(sNW1p * NL * 2);
  ushort* NW2p    = (ushort*)carve(sW2p * NL * 2);
  ushort* PWp     = (ushort*)carve(sPWp * 2);
  ushort* CWp     = (ushort*)carve(sCWp * 2);
  int* deg        = (int*)carve((size_t)NN * 4);
  int* row_ptr    = (int*)carve((size_t)(NN + 1) * 4);
  int* fill_pos   = (int*)carve((size_t)NN * 4);
  int* edge_ids   = (int*)carve((size_t)NE * 4);
  int* rowp       = (int*)carve((size_t)NE * 4);
  int* colp       = (int*)carve((size_t)NE * 4);

  hipMemsetAsync(deg, 0, (size_t)NN * 4, stream);
  hipMemsetAsync(fill_pos, 0, (size_t)NN * 4, stream);

  pos_copy_kernel<<<NN / 256, 256, 0, stream>>>(pos, pos_cur);
  hist_kernel<<<NE / 256, 256, 0, stream>>>(edge_index, deg);
  scan_kernel<<<1, 1024, 0, stream>>>(deg, row_ptr);
  fill_kernel<<<NE / 256, 256, 0, stream>>>(edge_index, row_ptr, fill_pos, edge_ids);
  perm_kernel<<<NE / 256, 256, 0, stream>>>(edge_index, edge_ids, edge_attr,
                                            rowp, colp, eap);

  packw_kernel<<<dim3(18, NL), 256, 0, stream>>>(edge_w1, W1p, 265, HD, KK1,
                                                 (size_t)265 * HD, sW1p);
  packw_kernel<<<dim3(8, NL), 256, 0, stream>>>(edge_w2, W2p, HD, HD, KK2,
                                                (size_t)HD * HD, sW2p);
  packw_kernel<<<dim3(8, NL), 256, 0, stream>>>(coord_w1, CW1p, HD, HD, KK2,
                                                (size_t)HD * HD, sW2p);
  packw_kernel<<<dim3(16, NL), 256, 0, stream>>>(node_w1, NW1p, 2 * HD, HD, KKN1,
                                                 (size_t)2 * HD * HD, sNW1p);
  packw_kernel<<<dim3(8, NL), 256, 0, stream>>>(node_w2, NW2p, HD, HD, KK2,
                                                (size_t)HD * HD, sW2p);
  packw_kernel<<<dim3(320, 1), 256, 0, stream>>>(prot_w, PWp, PED, PHD, KKP, 0, 0);
  packw_kernel<<<dim3(160, 1), 256, 0, stream>>>(comb_w1, CWp, HD + PHD, CHD, KKC, 0, 0);

  cvt_bf_kernel<<<NB * PED / (256 * 8), 256, 0, stream>>>(pe, pe_bf, NB * PED);

  emb_in_kernel<<<NN / 32, 256, 0, stream>>>(x, emb_in_w, emb_in_b, h, h_bf);

  for (int l = 0; l < NL; ++l) {
    geom_kernel<<<NE / 256, 256, 0, stream>>>(pos_cur, eap, rowp, colp, dnb, extra);
    edge_mfma_kernel<<<NE / 64, 256, 0, stream>>>(
        h_bf, extra, rowp, colp, dnb,
        W1p + (size_t)l * sW1p, edge_b1 + (size_t)l * HD,
        W2p + (size_t)l * sW2p, edge_b2 + (size_t)l * HD,
        att_w + (size_t)l * HD, att_b + l,
        CW1p + (size_t)l * sW2p, coord_b1 + (size_t)l * HD,
        coord_w2 + (size_t)l * HD,
        m_bf, trans);
    gather_kernel<<<NN / 4, 256, 0, stream>>>(m_bf, trans, row_ptr, agg_bf, pos_cur);
    node_mfma_kernel<<<NN / 64, 256, 0, stream>>>(
        h, h_bf, agg_bf,
        NW1p + (size_t)l * sNW1p, node_b1 + (size_t)l * HD,
        NW2p + (size_t)l * sW2p, node_b2 + (size_t)l * HD, h_bf);
  }

  pool_kernel<<<NB, 128, 0, stream>>>(h, emb_out_w, emb_out_b, c_in);
  gemm_head_kernel<<<dim3(NB / 64, PHD / 128), 256, 0, stream>>>(
      pe_bf, PWp, prot_b, c_in, PED, KKP, PHD / 16, HD + PHD, HD);
  gemm_head_kernel<<<dim3(NB / 64, CHD / 128), 256, 0, stream>>>(
      c_in, CWp, comb_b1, c1, HD + PHD, KKC, CHD / 16, CHD, 0);
  logits_kernel<<<NB / 4, 256, 0, stream>>>(c1, comb_w2, comb_b2, out);
}